// Round 2
// baseline (2318.226 us; speedup 1.0000x reference)
//
#include <hip/hip_runtime.h>
#include <hip/hip_bf16.h>

#define HW 65536
#define NCH 96
#define SCALE_Q 0.17677669529663687f

// ---------------- K0: relative-position MLP bias -> biasT[3][64][64] ----------------
__global__ void bias_kernel(const float* __restrict__ w1, const float* __restrict__ b1,
                            const float* __restrict__ w2, const float* __restrict__ b2,
                            float* __restrict__ biasT) {
    int gid = blockIdx.x * blockDim.x + threadIdx.x;
    if (gid >= 4096) return;
    int i = gid >> 6, j = gid & 63;
    float di = (float)((i >> 3) - (j >> 3));
    float dj = (float)((i & 7) - (j & 7));
    float r0 = (di > 0.f ? 1.f : (di < 0.f ? -1.f : 0.f)) * log1pf(fabsf(di));
    float r1 = (dj > 0.f ? 1.f : (dj < 0.f ? -1.f : 0.f)) * log1pf(fabsf(dj));
    float a0 = 0.f, a1 = 0.f, a2 = 0.f;
    for (int h = 0; h < 256; ++h) {
        float t = fmaf(w1[2 * h], r0, fmaf(w1[2 * h + 1], r1, b1[h]));
        t = fmaxf(t, 0.f);
        a0 = fmaf(w2[h], t, a0);
        a1 = fmaf(w2[256 + h], t, a1);
        a2 = fmaf(w2[512 + h], t, a2);
    }
    biasT[gid]            = a0 + b2[0];
    biasT[4096 + gid]     = a1 + b2[1];
    biasT[2 * 4096 + gid] = a2 + b2[2];
}

// ---------------- K0b: transpose QKV weights -> WT[c][288] (o: 0..191=QK, 192..287=V)
__global__ void wtrans_kernel(const float* __restrict__ QK_w, const float* __restrict__ V_w,
                              float* __restrict__ WT) {
    int idx = blockIdx.x * blockDim.x + threadIdx.x;
    if (idx >= 96 * 288) return;
    int c = idx / 288, o = idx - c * 288;
    WT[idx] = (o < 192) ? QK_w[o * 96 + c] : V_w[(o - 192) * 96 + c];
}

// ---------------- K1: fused QKV 1x1 conv + shifted-window attention ----------------
// block = 1 window (192 threads, wave = head, lane = token). Q/K never hit HBM.
// Writes: V (bf16) -> Vout[b][96][HW], attention out -> xr[b][96][HW] (= d_out).
__global__ __launch_bounds__(192) void fused_qkv_attn(
    const float* __restrict__ x, const float* __restrict__ WT,
    const float* __restrict__ QK_b, const float* __restrict__ V_b,
    const float* __restrict__ biasT,
    __hip_bfloat16* __restrict__ Vout, float* __restrict__ xr) {
    __shared__ float lds[12288];   // 48 KB union: Xw[96][64] | KV float4[3][1024]
    int tid = threadIdx.x;
    int head = tid >> 6;
    int lane = tid & 63;
    int win = blockIdx.x;
    int b = win >> 10;
    int wl = win & 1023;
    int wh = wl >> 5, ww = wl & 31;
    int ti = lane >> 3, tj = lane & 7;
    int ph = (wh * 8 + ti + 4) & 255;      // shifted-window gather (roll cancels on write-back)
    int pw = (ww * 8 + tj + 4) & 255;
    int pos = ph * 256 + pw;

    // stage x window: Xw[c][t]
    const float* xb = x + (size_t)b * (NCH * HW);
    for (int idx = tid; idx < 96 * 64; idx += 192) {
        int c = idx >> 6, t = idx & 63;
        int pph = (wh * 8 + (t >> 3) + 4) & 255;
        int ppw = (ww * 8 + (t & 7) + 4) & 255;
        lds[idx] = xb[(size_t)c * HW + pph * 256 + ppw];
    }
    __syncthreads();

    // per-lane GEMM: q,k,v (32 each) over 96 input channels
    float q[32], k[32], v[32];
#pragma unroll
    for (int i = 0; i < 32; ++i) { q[i] = 0.f; k[i] = 0.f; v[i] = 0.f; }
    const float* wtq = WT + head * 32;
    const float* wtk = WT + 96 + head * 32;
    const float* wtv = WT + 192 + head * 32;
#pragma unroll 1
    for (int c = 0; c < 96; ++c) {
        float xv = lds[c * 64 + lane];
        const float4* wq = (const float4*)(wtq + c * 288);
        const float4* wk = (const float4*)(wtk + c * 288);
        const float4* wv = (const float4*)(wtv + c * 288);
#pragma unroll
        for (int g = 0; g < 8; ++g) {
            float4 aq = wq[g], ak = wk[g], av = wv[g];
            q[4*g+0] = fmaf(aq.x, xv, q[4*g+0]);
            q[4*g+1] = fmaf(aq.y, xv, q[4*g+1]);
            q[4*g+2] = fmaf(aq.z, xv, q[4*g+2]);
            q[4*g+3] = fmaf(aq.w, xv, q[4*g+3]);
            k[4*g+0] = fmaf(ak.x, xv, k[4*g+0]);
            k[4*g+1] = fmaf(ak.y, xv, k[4*g+1]);
            k[4*g+2] = fmaf(ak.z, xv, k[4*g+2]);
            k[4*g+3] = fmaf(ak.w, xv, k[4*g+3]);
            v[4*g+0] = fmaf(av.x, xv, v[4*g+0]);
            v[4*g+1] = fmaf(av.y, xv, v[4*g+1]);
            v[4*g+2] = fmaf(av.z, xv, v[4*g+2]);
            v[4*g+3] = fmaf(av.w, xv, v[4*g+3]);
        }
    }
#pragma unroll
    for (int i = 0; i < 32; ++i) {
        q[i] = (q[i] + QK_b[head * 32 + i]) * SCALE_Q;
        k[i] = k[i] + QK_b[96 + head * 32 + i];
        v[i] = v[i] + V_b[head * 32 + i];
    }
    // V to global (bf16) for the depthwise conv
#pragma unroll
    for (int d = 0; d < 32; ++d)
        Vout[(size_t)(b * 96 + head * 32 + d) * HW + pos] = __float2bfloat16(v[d]);

    __syncthreads();   // Xw fully consumed; KV regions may overlap it

    // park K,V in per-wave LDS as [ch=c/4][t] float4
    float4* kw = (float4*)lds + head * 1024;
    float4* vw = kw + 512;
#pragma unroll
    for (int ch = 0; ch < 8; ++ch) {
        kw[ch * 64 + lane] = make_float4(k[4*ch], k[4*ch+1], k[4*ch+2], k[4*ch+3]);
        vw[ch * 64 + lane] = make_float4(v[4*ch], v[4*ch+1], v[4*ch+2], v[4*ch+3]);
    }

    // Swin mask region id (only boundary windows wh==31 / ww==31 are mixed)
    int rt = ((wh == 31) ? (ti < 4 ? 1 : 2) : 0) * 3 + ((ww == 31) ? (tj < 4 ? 1 : 2) : 0);
    const float* brow = biasT + head * 4096 + lane * 64;
    float a[64];
#pragma unroll
    for (int j = 0; j < 64; ++j) {
        float s = 0.f;
#pragma unroll
        for (int ch = 0; ch < 8; ++ch) {
            float4 kv = kw[ch * 64 + j];   // uniform address -> LDS broadcast
            s = fmaf(q[4*ch+0], kv.x, s);
            s = fmaf(q[4*ch+1], kv.y, s);
            s = fmaf(q[4*ch+2], kv.z, s);
            s = fmaf(q[4*ch+3], kv.w, s);
        }
        int rj = ((wh == 31) ? ((j >> 3) < 4 ? 1 : 2) : 0) * 3 +
                 ((ww == 31) ? ((j & 7) < 4 ? 1 : 2) : 0);
        s += brow[j];
        if (rj != rt) s -= 100.f;
        a[j] = s;
    }
    // in-lane softmax
    float mmax = a[0];
#pragma unroll
    for (int j = 1; j < 64; ++j) mmax = fmaxf(mmax, a[j]);
    float ssum = 0.f;
#pragma unroll
    for (int j = 0; j < 64; ++j) { a[j] = __expf(a[j] - mmax); ssum += a[j]; }
    float inv = 1.f / ssum;
    float acc[32];
#pragma unroll
    for (int d = 0; d < 32; ++d) acc[d] = 0.f;
#pragma unroll
    for (int j = 0; j < 64; ++j) {
        float p = a[j] * inv;
#pragma unroll
        for (int ch = 0; ch < 8; ++ch) {
            float4 vv = vw[ch * 64 + j];   // uniform broadcast
            acc[4*ch+0] = fmaf(p, vv.x, acc[4*ch+0]);
            acc[4*ch+1] = fmaf(p, vv.y, acc[4*ch+1]);
            acc[4*ch+2] = fmaf(p, vv.z, acc[4*ch+2]);
            acc[4*ch+3] = fmaf(p, vv.w, acc[4*ch+3]);
        }
    }
    float* xrb = xr + (size_t)(b * 96 + head * 32) * HW + pos;
#pragma unroll
    for (int d = 0; d < 32; ++d) xrb[(size_t)d * HW] = acc[d];
}

// ---------------- K2: depthwise 5x5 reflect conv on V(bf16) + xr -> T (in place on d_out)
__global__ __launch_bounds__(256) void dwconv_kernel(const __hip_bfloat16* __restrict__ V,
                                                     const float* __restrict__ dw_w,
                                                     const float* __restrict__ dw_b,
                                                     float* __restrict__ T) {
    int bx = blockIdx.x;
    int tile = bx & 255;          // 256 tiles (64x4) per 256x256 plane
    int plane = bx >> 8;          // b*96 + c
    int c = plane % 96;
    int tw = tile & 3, th = tile >> 2;
    int w = tw * 64 + (threadIdx.x & 63);
    int h = th * 4 + (threadIdx.x >> 6);
    const __hip_bfloat16* Vp = V + (size_t)plane * HW;
    const float* wt = dw_w + c * 25;
    float acc = dw_b[c];
#pragma unroll
    for (int dy = -2; dy <= 2; ++dy) {
        int hh = h + dy;
        hh = hh < 0 ? -hh : (hh > 255 ? 510 - hh : hh);
#pragma unroll
        for (int dx = -2; dx <= 2; ++dx) {
            int wp = w + dx;
            wp = wp < 0 ? -wp : (wp > 255 ? 510 - wp : wp);
            acc = fmaf(wt[(dy + 2) * 5 + (dx + 2)], __bfloat162float(Vp[hh * 256 + wp]), acc);
        }
    }
    size_t o = (size_t)plane * HW + h * 256 + w;
    T[o] = acc + T[o];   // T currently holds xr; same-element read-modify-write
}

// ---------------- K3: projection 1x1 conv (in place on d_out) ----------------
template <int OCH, int NCHUNK>
__global__ __launch_bounds__(256) void conv1x1_kernel(
    const float* __restrict__ x,
    const float* __restrict__ wA, const float* __restrict__ bA,
    float* __restrict__ y, int xBstride, int yBstride) {
    __shared__ float Xs[96][128];
    __shared__ float WsT[96][32];
    int bx = blockIdx.x;
    int b  = bx >> 9;
    int m0 = (bx & 511) << 7;
    int tid = threadIdx.x;
    const float* xb = x + (size_t)b * xBstride + m0;
    for (int idx = tid; idx < 96 * 32; idx += 256) {
        int c = idx >> 5, mm = idx & 31;
        float4 vv = *(const float4*)(xb + (size_t)c * HW + mm * 4);
        *(float4*)(&Xs[c][mm * 4]) = vv;
    }
    __syncthreads();
    int m = tid & 127, oh = tid >> 7;
    for (int oc = 0; oc < NCHUNK; ++oc) {
        for (int idx = tid; idx < 32 * 96; idx += 256) {
            int kk = idx / 96, c = idx - kk * 96;
            WsT[c][kk] = wA[(oc * 32 + kk) * 96 + c];
        }
        __syncthreads();
        float acc[16];
#pragma unroll
        for (int u = 0; u < 16; ++u) acc[u] = 0.f;
#pragma unroll 4
        for (int c = 0; c < 96; ++c) {
            float xv = Xs[c][m];
            const float4* wrow = (const float4*)(&WsT[c][oh * 16]);
#pragma unroll
            for (int g = 0; g < 4; ++g) {
                float4 wv = wrow[g];
                acc[g * 4 + 0] = fmaf(wv.x, xv, acc[g * 4 + 0]);
                acc[g * 4 + 1] = fmaf(wv.y, xv, acc[g * 4 + 1]);
                acc[g * 4 + 2] = fmaf(wv.z, xv, acc[g * 4 + 2]);
                acc[g * 4 + 3] = fmaf(wv.w, xv, acc[g * 4 + 3]);
            }
        }
#pragma unroll
        for (int u = 0; u < 16; ++u) {
            int o = oc * 32 + oh * 16 + u;
            y[(size_t)b * yBstride + (size_t)o * HW + m0 + m] = acc[u] + bA[o];
        }
        __syncthreads();
    }
}

extern "C" void kernel_launch(void* const* d_in, const int* in_sizes, int n_in,
                              void* d_out, int out_size, void* d_ws, size_t ws_size,
                              hipStream_t stream) {
    const float* x      = (const float*)d_in[0];
    const float* V_w    = (const float*)d_in[1];
    const float* V_b    = (const float*)d_in[2];
    const float* QK_w   = (const float*)d_in[3];
    const float* QK_b   = (const float*)d_in[4];
    const float* proj_w = (const float*)d_in[5];
    const float* proj_b = (const float*)d_in[6];
    const float* dw_w   = (const float*)d_in[7];
    const float* dw_b   = (const float*)d_in[8];
    const float* mw1    = (const float*)d_in[9];
    const float* mb1    = (const float*)d_in[10];
    const float* mw2    = (const float*)d_in[11];
    const float* mb2    = (const float*)d_in[12];
    float* out = (float*)d_out;

    // workspace layout (total ~96.2 MiB):
    char* ws = (char*)d_ws;
    __hip_bfloat16* Vbuf = (__hip_bfloat16*)ws;                 // 8*96*65536*2 = 100663296 B
    float* biasT = (float*)(ws + 100663296);                    // 49152 B
    float* WT    = (float*)(ws + 100663296 + 49152);            // 96*288*4 = 110592 B

    bias_kernel<<<16, 256, 0, stream>>>(mw1, mb1, mw2, mb2, biasT);
    wtrans_kernel<<<108, 256, 0, stream>>>(QK_w, V_w, WT);
    // fused QKV conv + attention: xr -> d_out, V(bf16) -> ws
    fused_qkv_attn<<<8192, 192, 0, stream>>>(x, WT, QK_b, V_b, biasT, Vbuf, out);
    // depthwise conv + residual, in place on d_out
    dwconv_kernel<<<196608, 256, 0, stream>>>(Vbuf, dw_w, dw_b, out);
    // projection, in place on d_out
    conv1x1_kernel<96, 3><<<4096, 256, 0, stream>>>(out, proj_w, proj_b, out,
                                                    96 * HW, 96 * HW);
}

// Round 3
// 1594.562 us; speedup vs baseline: 1.4538x; 1.4538x over previous
//
#include <hip/hip_runtime.h>
#include <hip/hip_bf16.h>

#define HW 65536
#define NCH 96
#define SCALE_Q 0.17677669529663687f

// ---------------- K0: relative-position MLP bias -> biasT[3][64(key j)][64(query i)] ----
__global__ void bias_kernel(const float* __restrict__ w1, const float* __restrict__ b1,
                            const float* __restrict__ w2, const float* __restrict__ b2,
                            float* __restrict__ biasT) {
    int gid = blockIdx.x * blockDim.x + threadIdx.x;
    if (gid >= 4096) return;
    int i = gid >> 6, j = gid & 63;
    float di = (float)((i >> 3) - (j >> 3));
    float dj = (float)((i & 7) - (j & 7));
    float r0 = (di > 0.f ? 1.f : (di < 0.f ? -1.f : 0.f)) * log1pf(fabsf(di));
    float r1 = (dj > 0.f ? 1.f : (dj < 0.f ? -1.f : 0.f)) * log1pf(fabsf(dj));
    float a0 = 0.f, a1 = 0.f, a2 = 0.f;
    for (int h = 0; h < 256; ++h) {
        float t = fmaf(w1[2 * h], r0, fmaf(w1[2 * h + 1], r1, b1[h]));
        t = fmaxf(t, 0.f);
        a0 = fmaf(w2[h], t, a0);
        a1 = fmaf(w2[256 + h], t, a1);
        a2 = fmaf(w2[512 + h], t, a2);
    }
    // transposed store: [head][j][i] so attention reads are lane-coalesced over i
    biasT[j * 64 + i]            = a0 + b2[0];
    biasT[4096 + j * 64 + i]     = a1 + b2[1];
    biasT[2 * 4096 + j * 64 + i] = a2 + b2[2];
}

// ---------------- K0b: transpose weights.
// WTqkv[c][288] (o: 0..191=QK rows, 192..287=V rows); WTproj[c][96].
__global__ void wtrans_kernel(const float* __restrict__ QK_w, const float* __restrict__ V_w,
                              const float* __restrict__ proj_w,
                              float* __restrict__ WTqkv, float* __restrict__ WTproj) {
    int idx = blockIdx.x * blockDim.x + threadIdx.x;
    if (idx < 96 * 288) {
        int c = idx / 288, o = idx - c * 288;
        WTqkv[idx] = (o < 192) ? QK_w[o * 96 + c] : V_w[(o - 192) * 96 + c];
    } else if (idx < 96 * 288 + 96 * 96) {
        int r = idx - 96 * 288;
        int c = r / 96, o = r - c * 96;
        WTproj[r] = proj_w[o * 96 + c];
    }
}

// ---------------- K1: fused QKV 1x1 conv + shifted-window attention ----------------
// block = 1 window (192 threads, wave = head, lane = token). Q/K never hit HBM.
// Weights read via the SCALAR pipe (wave-uniform address via readfirstlane).
__global__ __launch_bounds__(192) void fused_qkv_attn(
    const float* __restrict__ x, const float* __restrict__ WT,
    const float* __restrict__ QK_b, const float* __restrict__ V_b,
    const float* __restrict__ biasT,
    __hip_bfloat16* __restrict__ Vout, float* __restrict__ xr) {
    __shared__ float lds[12288];   // 48 KB union: Xw[96][64] | KV float4[3][1024]
    int tid = threadIdx.x;
    int head = tid >> 6;
    int lane = tid & 63;
    int win = blockIdx.x;
    int b = win >> 10;
    int wl = win & 1023;
    int wh = wl >> 5, ww = wl & 31;
    int ti = lane >> 3, tj = lane & 7;
    int ph = (wh * 8 + ti + 4) & 255;      // shifted-window gather (roll cancels on write-back)
    int pw = (ww * 8 + tj + 4) & 255;
    int pos = ph * 256 + pw;

    // stage x window: Xw[c][t]
    const float* xb = x + (size_t)b * (NCH * HW);
    for (int idx = tid; idx < 96 * 64; idx += 192) {
        int c = idx >> 6, t = idx & 63;
        int pph = (wh * 8 + (t >> 3) + 4) & 255;
        int ppw = (ww * 8 + (t & 7) + 4) & 255;
        lds[idx] = xb[(size_t)c * HW + pph * 256 + ppw];
    }
    __syncthreads();

    // per-lane GEMM: q,k,v (32 each) over 96 input channels; weights via scalar loads
    int headU = __builtin_amdgcn_readfirstlane(head);
    float q[32], k[32], v[32];
#pragma unroll
    for (int i = 0; i < 32; ++i) { q[i] = 0.f; k[i] = 0.f; v[i] = 0.f; }
    const float* wbase = WT + headU * 32;
#pragma unroll 2
    for (int c = 0; c < 96; ++c) {
        float xv = lds[c * 64 + lane];
        const float* w = wbase + c * 288;
#pragma unroll
        for (int i = 0; i < 32; ++i) {
            q[i] = fmaf(w[i],       xv, q[i]);
            k[i] = fmaf(w[96 + i],  xv, k[i]);
            v[i] = fmaf(w[192 + i], xv, v[i]);
        }
    }
#pragma unroll
    for (int i = 0; i < 32; ++i) {
        q[i] = (q[i] + QK_b[headU * 32 + i]) * SCALE_Q;
        k[i] = k[i] + QK_b[96 + headU * 32 + i];
        v[i] = v[i] + V_b[headU * 32 + i];
    }
    // V to global (bf16) for the depthwise conv
#pragma unroll
    for (int d = 0; d < 32; ++d)
        Vout[(size_t)(b * 96 + head * 32 + d) * HW + pos] = __float2bfloat16(v[d]);

    __syncthreads();   // Xw fully consumed; KV regions overlap it

    // park K,V in per-wave LDS as [ch=c/4][t] float4
    float4* kw = (float4*)lds + head * 1024;
    float4* vw = kw + 512;
#pragma unroll
    for (int ch = 0; ch < 8; ++ch) {
        kw[ch * 64 + lane] = make_float4(k[4*ch], k[4*ch+1], k[4*ch+2], k[4*ch+3]);
        vw[ch * 64 + lane] = make_float4(v[4*ch], v[4*ch+1], v[4*ch+2], v[4*ch+3]);
    }

    // Swin mask region id (only boundary windows wh==31 / ww==31 are mixed)
    int rt = ((wh == 31) ? (ti < 4 ? 1 : 2) : 0) * 3 + ((ww == 31) ? (tj < 4 ? 1 : 2) : 0);
    const float* bT = biasT + headU * 4096 + lane;   // [j][lane] coalesced
    float a[64];
#pragma unroll
    for (int j = 0; j < 64; ++j) {
        float s = 0.f;
#pragma unroll
        for (int ch = 0; ch < 8; ++ch) {
            float4 kv = kw[ch * 64 + j];   // uniform address -> LDS broadcast
            s = fmaf(q[4*ch+0], kv.x, s);
            s = fmaf(q[4*ch+1], kv.y, s);
            s = fmaf(q[4*ch+2], kv.z, s);
            s = fmaf(q[4*ch+3], kv.w, s);
        }
        int rj = ((wh == 31) ? ((j >> 3) < 4 ? 1 : 2) : 0) * 3 +
                 ((ww == 31) ? ((j & 7) < 4 ? 1 : 2) : 0);
        s += bT[j * 64];
        if (rj != rt) s -= 100.f;
        a[j] = s;
    }
    // in-lane softmax
    float mmax = a[0];
#pragma unroll
    for (int j = 1; j < 64; ++j) mmax = fmaxf(mmax, a[j]);
    float ssum = 0.f;
#pragma unroll
    for (int j = 0; j < 64; ++j) { a[j] = __expf(a[j] - mmax); ssum += a[j]; }
    float inv = 1.f / ssum;
    float acc[32];
#pragma unroll
    for (int d = 0; d < 32; ++d) acc[d] = 0.f;
#pragma unroll
    for (int j = 0; j < 64; ++j) {
        float p = a[j] * inv;
#pragma unroll
        for (int ch = 0; ch < 8; ++ch) {
            float4 vv = vw[ch * 64 + j];   // uniform broadcast
            acc[4*ch+0] = fmaf(p, vv.x, acc[4*ch+0]);
            acc[4*ch+1] = fmaf(p, vv.y, acc[4*ch+1]);
            acc[4*ch+2] = fmaf(p, vv.z, acc[4*ch+2]);
            acc[4*ch+3] = fmaf(p, vv.w, acc[4*ch+3]);
        }
    }
    float* xrb = xr + (size_t)(b * 96 + head * 32) * HW + pos;
#pragma unroll
    for (int d = 0; d < 32; ++d) xrb[(size_t)d * HW] = acc[d];
}

// ---------------- K2: depthwise 5x5 reflect conv on V(bf16) + xr -> T (in place on d_out)
__global__ __launch_bounds__(256) void dwconv_kernel(const __hip_bfloat16* __restrict__ V,
                                                     const float* __restrict__ dw_w,
                                                     const float* __restrict__ dw_b,
                                                     float* __restrict__ T) {
    int bx = blockIdx.x;
    int tile = bx & 255;          // 256 tiles (64x4) per 256x256 plane
    int plane = bx >> 8;          // b*96 + c
    int c = plane % 96;
    int tw = tile & 3, th = tile >> 2;
    int w = tw * 64 + (threadIdx.x & 63);
    int h = th * 4 + (threadIdx.x >> 6);
    const __hip_bfloat16* Vp = V + (size_t)plane * HW;
    const float* wt = dw_w + c * 25;
    float acc = dw_b[c];
#pragma unroll
    for (int dy = -2; dy <= 2; ++dy) {
        int hh = h + dy;
        hh = hh < 0 ? -hh : (hh > 255 ? 510 - hh : hh);
#pragma unroll
        for (int dx = -2; dx <= 2; ++dx) {
            int wp = w + dx;
            wp = wp < 0 ? -wp : (wp > 255 ? 510 - wp : wp);
            acc = fmaf(wt[(dy + 2) * 5 + (dx + 2)], __bfloat162float(Vp[hh * 256 + wp]), acc);
        }
    }
    size_t o = (size_t)plane * HW + h * 256 + w;
    T[o] = acc + T[o];   // T currently holds xr; same-element read-modify-write
}

// ---------------- K3: projection 1x1 conv, scalar-pipe weights (in place on d_out) ----
__global__ __launch_bounds__(256) void proj_kernel(const float* __restrict__ x,
                                                   const float* __restrict__ WTp,  // [c][96]
                                                   const float* __restrict__ bA,
                                                   float* __restrict__ y) {
    __shared__ float Xs[96][128];   // 48 KB
    int bx = blockIdx.x;
    int b  = bx >> 9;
    int m0 = (bx & 511) << 7;
    int tid = threadIdx.x;
    const float* xb = x + (size_t)b * (96 * HW) + m0;
    for (int idx = tid; idx < 96 * 32; idx += 256) {
        int c = idx >> 5, mm = idx & 31;
        float4 vv = *(const float4*)(xb + (size_t)c * HW + mm * 4);
        *(float4*)(&Xs[c][mm * 4]) = vv;
    }
    __syncthreads();
    int m = tid & 127;
    int ohU = __builtin_amdgcn_readfirstlane(tid >> 7);   // wave-uniform {0,1}
    for (int oc = 0; oc < 3; ++oc) {
        float acc[16];
#pragma unroll
        for (int u = 0; u < 16; ++u) acc[u] = 0.f;
        const float* wbase = WTp + oc * 32 + ohU * 16;
#pragma unroll 4
        for (int c = 0; c < 96; ++c) {
            float xv = Xs[c][m];
            const float* w = wbase + c * 96;
#pragma unroll
            for (int u = 0; u < 16; ++u) acc[u] = fmaf(w[u], xv, acc[u]);
        }
#pragma unroll
        for (int u = 0; u < 16; ++u) {
            int o = oc * 32 + ohU * 16 + u;
            y[(size_t)b * (96 * HW) + (size_t)o * HW + m0 + m] = acc[u] + bA[o];
        }
    }
}

extern "C" void kernel_launch(void* const* d_in, const int* in_sizes, int n_in,
                              void* d_out, int out_size, void* d_ws, size_t ws_size,
                              hipStream_t stream) {
    const float* x      = (const float*)d_in[0];
    const float* V_w    = (const float*)d_in[1];
    const float* V_b    = (const float*)d_in[2];
    const float* QK_w   = (const float*)d_in[3];
    const float* QK_b   = (const float*)d_in[4];
    const float* proj_w = (const float*)d_in[5];
    const float* proj_b = (const float*)d_in[6];
    const float* dw_w   = (const float*)d_in[7];
    const float* dw_b   = (const float*)d_in[8];
    const float* mw1    = (const float*)d_in[9];
    const float* mb1    = (const float*)d_in[10];
    const float* mw2    = (const float*)d_in[11];
    const float* mb2    = (const float*)d_in[12];
    float* out = (float*)d_out;

    // workspace layout (~100.9 MiB)
    char* ws = (char*)d_ws;
    __hip_bfloat16* Vbuf = (__hip_bfloat16*)ws;                   // 100663296 B
    float* biasT  = (float*)(ws + 100663296);                     // 49152 B
    float* WTqkv  = (float*)(ws + 100663296 + 49152);             // 110592 B
    float* WTproj = (float*)(ws + 100663296 + 49152 + 110592);    // 36864 B

    bias_kernel<<<16, 256, 0, stream>>>(mw1, mb1, mw2, mb2, biasT);
    wtrans_kernel<<<144, 256, 0, stream>>>(QK_w, V_w, proj_w, WTqkv, WTproj);
    fused_qkv_attn<<<8192, 192, 0, stream>>>(x, WTqkv, QK_b, V_b, biasT, Vbuf, out);
    dwconv_kernel<<<196608, 256, 0, stream>>>(Vbuf, dw_w, dw_b, out);
    proj_kernel<<<4096, 256, 0, stream>>>(out, WTproj, proj_b, out);
}

// Round 4
// 1147.091 us; speedup vs baseline: 2.0210x; 1.3901x over previous
//
#include <hip/hip_runtime.h>
#include <hip/hip_bf16.h>

#define HW 65536
#define NCH 96
#define SCALE_Q 0.17677669529663687f

// ---------------- K0: relative-position MLP bias -> biasT[3][64(key j)][64(query i)] ----
__global__ void bias_kernel(const float* __restrict__ w1, const float* __restrict__ b1,
                            const float* __restrict__ w2, const float* __restrict__ b2,
                            float* __restrict__ biasT) {
    int gid = blockIdx.x * blockDim.x + threadIdx.x;
    if (gid >= 4096) return;
    int i = gid >> 6, j = gid & 63;
    float di = (float)((i >> 3) - (j >> 3));
    float dj = (float)((i & 7) - (j & 7));
    float r0 = (di > 0.f ? 1.f : (di < 0.f ? -1.f : 0.f)) * log1pf(fabsf(di));
    float r1 = (dj > 0.f ? 1.f : (dj < 0.f ? -1.f : 0.f)) * log1pf(fabsf(dj));
    float a0 = 0.f, a1 = 0.f, a2 = 0.f;
    for (int h = 0; h < 256; ++h) {
        float t = fmaf(w1[2 * h], r0, fmaf(w1[2 * h + 1], r1, b1[h]));
        t = fmaxf(t, 0.f);
        a0 = fmaf(w2[h], t, a0);
        a1 = fmaf(w2[256 + h], t, a1);
        a2 = fmaf(w2[512 + h], t, a2);
    }
    // transposed store: [head][j][i] so attention reads are lane-coalesced over i
    biasT[j * 64 + i]            = a0 + b2[0];
    biasT[4096 + j * 64 + i]     = a1 + b2[1];
    biasT[2 * 4096 + j * 64 + i] = a2 + b2[2];
}

// ---------------- K0b: transpose weights.
// WTqkv[c][288] (o: 0..191=QK rows, 192..287=V rows); WTproj[c][96].
__global__ void wtrans_kernel(const float* __restrict__ QK_w, const float* __restrict__ V_w,
                              const float* __restrict__ proj_w,
                              float* __restrict__ WTqkv, float* __restrict__ WTproj) {
    int idx = blockIdx.x * blockDim.x + threadIdx.x;
    if (idx < 96 * 288) {
        int c = idx / 288, o = idx - c * 288;
        WTqkv[idx] = (o < 192) ? QK_w[o * 96 + c] : V_w[(o - 192) * 96 + c];
    } else if (idx < 96 * 288 + 96 * 96) {
        int r = idx - 96 * 288;
        int c = r / 96, o = r - c * 96;
        WTproj[r] = proj_w[o * 96 + c];
    }
}

// ---------------- K1: fused QKV 1x1 conv + shifted-window attention ----------------
// block = 1 window (192 threads, wave = head, lane = token). Q/K never hit HBM.
// Weights via SCALAR pipe. LDS = 24 KB: Xw[96][64] union 3x(8 KB per-head K/V
// time-shared region) -> 6 blocks/CU instead of 2-3.
__global__ __launch_bounds__(192) void fused_qkv_attn(
    const float* __restrict__ x, const float* __restrict__ WT,
    const float* __restrict__ QK_b, const float* __restrict__ V_b,
    const float* __restrict__ biasT,
    __hip_bfloat16* __restrict__ Vout, float* __restrict__ xr) {
    __shared__ float lds[6144];   // 24 KB
    int tid = threadIdx.x;
    int head = tid >> 6;
    int lane = tid & 63;
    int win = blockIdx.x;
    int b = win >> 10;
    int wl = win & 1023;
    int wh = wl >> 5, ww = wl & 31;
    int ti = lane >> 3, tj = lane & 7;
    int ph = (wh * 8 + ti + 4) & 255;      // shifted-window gather (roll cancels on write-back)
    int pw = (ww * 8 + tj + 4) & 255;
    int pos = ph * 256 + pw;

    // stage x window: Xw[c][t]
    const float* xb = x + (size_t)b * (NCH * HW);
    for (int idx = tid; idx < 96 * 64; idx += 192) {
        int c = idx >> 6, t = idx & 63;
        int pph = (wh * 8 + (t >> 3) + 4) & 255;
        int ppw = (ww * 8 + (t & 7) + 4) & 255;
        lds[idx] = xb[(size_t)c * HW + pph * 256 + ppw];
    }
    __syncthreads();

    // per-lane GEMM: q,k,v (32 each) over 96 input channels; weights via scalar loads
    int headU = __builtin_amdgcn_readfirstlane(head);
    float q[32], k[32], v[32];
#pragma unroll
    for (int i = 0; i < 32; ++i) { q[i] = 0.f; k[i] = 0.f; v[i] = 0.f; }
    const float* wbase = WT + headU * 32;
#pragma unroll 2
    for (int c = 0; c < 96; ++c) {
        float xv = lds[c * 64 + lane];
        const float* w = wbase + c * 288;
#pragma unroll
        for (int i = 0; i < 32; ++i) {
            q[i] = fmaf(w[i],       xv, q[i]);
            k[i] = fmaf(w[96 + i],  xv, k[i]);
            v[i] = fmaf(w[192 + i], xv, v[i]);
        }
    }
#pragma unroll
    for (int i = 0; i < 32; ++i) {
        q[i] = (q[i] + QK_b[headU * 32 + i]) * SCALE_Q;
        k[i] = k[i] + QK_b[96 + headU * 32 + i];
        v[i] = v[i] + V_b[headU * 32 + i];
    }
    // V to global (bf16) for the depthwise conv
#pragma unroll
    for (int d = 0; d < 32; ++d)
        Vout[(size_t)(b * 96 + head * 32 + d) * HW + pos] = __float2bfloat16(v[d]);

    __syncthreads();   // Xw fully consumed by all waves; KV regions overlap it

    // per-head 8 KB region, time-shared between K and V
    float4* kvr = (float4*)lds + head * 512;
#pragma unroll
    for (int ch = 0; ch < 8; ++ch)
        kvr[ch * 64 + lane] = make_float4(k[4*ch], k[4*ch+1], k[4*ch+2], k[4*ch+3]);
    __syncthreads();

    // Swin mask region id (only boundary windows wh==31 / ww==31 are mixed)
    int rt = ((wh == 31) ? (ti < 4 ? 1 : 2) : 0) * 3 + ((ww == 31) ? (tj < 4 ? 1 : 2) : 0);
    const float* bT = biasT + headU * 4096 + lane;   // [j][lane] coalesced
    float a[64];
#pragma unroll
    for (int j = 0; j < 64; ++j) {
        float s = 0.f;
#pragma unroll
        for (int ch = 0; ch < 8; ++ch) {
            float4 kv = kvr[ch * 64 + j];   // uniform address -> LDS broadcast
            s = fmaf(q[4*ch+0], kv.x, s);
            s = fmaf(q[4*ch+1], kv.y, s);
            s = fmaf(q[4*ch+2], kv.z, s);
            s = fmaf(q[4*ch+3], kv.w, s);
        }
        int rj = ((wh == 31) ? ((j >> 3) < 4 ? 1 : 2) : 0) * 3 +
                 ((ww == 31) ? ((j & 7) < 4 ? 1 : 2) : 0);
        s += bT[j * 64];
        if (rj != rt) s -= 100.f;
        a[j] = s;
    }
    // in-lane softmax
    float mmax = a[0];
#pragma unroll
    for (int j = 1; j < 64; ++j) mmax = fmaxf(mmax, a[j]);
    float ssum = 0.f;
#pragma unroll
    for (int j = 0; j < 64; ++j) { a[j] = __expf(a[j] - mmax); ssum += a[j]; }
    float inv = 1.f / ssum;

    __syncthreads();   // all QK reads done; overwrite region with V
#pragma unroll
    for (int ch = 0; ch < 8; ++ch)
        kvr[ch * 64 + lane] = make_float4(v[4*ch], v[4*ch+1], v[4*ch+2], v[4*ch+3]);
    __syncthreads();

    float acc[32];
#pragma unroll
    for (int d = 0; d < 32; ++d) acc[d] = 0.f;
#pragma unroll
    for (int j = 0; j < 64; ++j) {
        float p = a[j] * inv;
#pragma unroll
        for (int ch = 0; ch < 8; ++ch) {
            float4 vv = kvr[ch * 64 + j];   // uniform broadcast
            acc[4*ch+0] = fmaf(p, vv.x, acc[4*ch+0]);
            acc[4*ch+1] = fmaf(p, vv.y, acc[4*ch+1]);
            acc[4*ch+2] = fmaf(p, vv.z, acc[4*ch+2]);
            acc[4*ch+3] = fmaf(p, vv.w, acc[4*ch+3]);
        }
    }
    float* xrb = xr + (size_t)(b * 96 + head * 32) * HW + pos;
#pragma unroll
    for (int d = 0; d < 32; ++d) xrb[(size_t)d * HW] = acc[d];
}

// ---------------- K2: depthwise 5x5 reflect conv on V(bf16) + xr -> T (in place on d_out)
__global__ __launch_bounds__(256) void dwconv_kernel(const __hip_bfloat16* __restrict__ V,
                                                     const float* __restrict__ dw_w,
                                                     const float* __restrict__ dw_b,
                                                     float* __restrict__ T) {
    int bx = blockIdx.x;
    int tile = bx & 255;          // 256 tiles (64x4) per 256x256 plane
    int plane = bx >> 8;          // b*96 + c
    int c = plane % 96;
    int tw = tile & 3, th = tile >> 2;
    int w = tw * 64 + (threadIdx.x & 63);
    int h = th * 4 + (threadIdx.x >> 6);
    const __hip_bfloat16* Vp = V + (size_t)plane * HW;
    const float* wt = dw_w + c * 25;
    float acc = dw_b[c];
#pragma unroll
    for (int dy = -2; dy <= 2; ++dy) {
        int hh = h + dy;
        hh = hh < 0 ? -hh : (hh > 255 ? 510 - hh : hh);
#pragma unroll
        for (int dx = -2; dx <= 2; ++dx) {
            int wp = w + dx;
            wp = wp < 0 ? -wp : (wp > 255 ? 510 - wp : wp);
            acc = fmaf(wt[(dy + 2) * 5 + (dx + 2)], __bfloat162float(Vp[hh * 256 + wp]), acc);
        }
    }
    size_t o = (size_t)plane * HW + h * 256 + w;
    T[o] = acc + T[o];   // T currently holds xr; same-element read-modify-write
}

// ---------------- K3: projection 1x1 conv, scalar-pipe weights (in place on d_out) ----
__global__ __launch_bounds__(256) void proj_kernel(const float* __restrict__ x,
                                                   const float* __restrict__ WTp,  // [c][96]
                                                   const float* __restrict__ bA,
                                                   float* __restrict__ y) {
    __shared__ float Xs[96][128];   // 48 KB
    int bx = blockIdx.x;
    int b  = bx >> 9;
    int m0 = (bx & 511) << 7;
    int tid = threadIdx.x;
    const float* xb = x + (size_t)b * (96 * HW) + m0;
    for (int idx = tid; idx < 96 * 32; idx += 256) {
        int c = idx >> 5, mm = idx & 31;
        float4 vv = *(const float4*)(xb + (size_t)c * HW + mm * 4);
        *(float4*)(&Xs[c][mm * 4]) = vv;
    }
    __syncthreads();
    int m = tid & 127;
    int ohU = __builtin_amdgcn_readfirstlane(tid >> 7);   // wave-uniform {0,1}
    for (int oc = 0; oc < 3; ++oc) {
        float acc[16];
#pragma unroll
        for (int u = 0; u < 16; ++u) acc[u] = 0.f;
        const float* wbase = WTp + oc * 32 + ohU * 16;
#pragma unroll 4
        for (int c = 0; c < 96; ++c) {
            float xv = Xs[c][m];
            const float* w = wbase + c * 96;
#pragma unroll
            for (int u = 0; u < 16; ++u) acc[u] = fmaf(w[u], xv, acc[u]);
        }
#pragma unroll
        for (int u = 0; u < 16; ++u) {
            int o = oc * 32 + ohU * 16 + u;
            y[(size_t)b * (96 * HW) + (size_t)o * HW + m0 + m] = acc[u] + bA[o];
        }
    }
}

extern "C" void kernel_launch(void* const* d_in, const int* in_sizes, int n_in,
                              void* d_out, int out_size, void* d_ws, size_t ws_size,
                              hipStream_t stream) {
    const float* x      = (const float*)d_in[0];
    const float* V_w    = (const float*)d_in[1];
    const float* V_b    = (const float*)d_in[2];
    const float* QK_w   = (const float*)d_in[3];
    const float* QK_b   = (const float*)d_in[4];
    const float* proj_w = (const float*)d_in[5];
    const float* proj_b = (const float*)d_in[6];
    const float* dw_w   = (const float*)d_in[7];
    const float* dw_b   = (const float*)d_in[8];
    const float* mw1    = (const float*)d_in[9];
    const float* mb1    = (const float*)d_in[10];
    const float* mw2    = (const float*)d_in[11];
    const float* mb2    = (const float*)d_in[12];
    float* out = (float*)d_out;

    // workspace layout (~100.9 MiB)
    char* ws = (char*)d_ws;
    __hip_bfloat16* Vbuf = (__hip_bfloat16*)ws;                   // 100663296 B
    float* biasT  = (float*)(ws + 100663296);                     // 49152 B
    float* WTqkv  = (float*)(ws + 100663296 + 49152);             // 110592 B
    float* WTproj = (float*)(ws + 100663296 + 49152 + 110592);    // 36864 B

    bias_kernel<<<16, 256, 0, stream>>>(mw1, mb1, mw2, mb2, biasT);
    wtrans_kernel<<<144, 256, 0, stream>>>(QK_w, V_w, proj_w, WTqkv, WTproj);
    fused_qkv_attn<<<8192, 192, 0, stream>>>(x, WTqkv, QK_b, V_b, biasT, Vbuf, out);
    dwconv_kernel<<<196608, 256, 0, stream>>>(Vbuf, dw_w, dw_b, out);
    proj_kernel<<<4096, 256, 0, stream>>>(out, WTproj, proj_b, out);
}

// Round 5
// 938.327 us; speedup vs baseline: 2.4706x; 1.2225x over previous
//
#include <hip/hip_runtime.h>
#include <hip/hip_bf16.h>

#define HW 65536
#define SCALE_Q 0.17677669529663687f

typedef __bf16 bf16x8 __attribute__((ext_vector_type(8)));
typedef float f32x4 __attribute__((ext_vector_type(4)));

// ---------------- K0: rel-pos MLP bias, emitted directly in C-fragment layout ----------
// biasF[h][mi][ni][r][lane] = bias(h, i=mi*16+(lane>>4)*4+r, j=ni*16+(lane&15))
__global__ void bias_kernel(const float* __restrict__ w1, const float* __restrict__ b1,
                            const float* __restrict__ w2, const float* __restrict__ b2,
                            float* __restrict__ biasF) {
    int gid = blockIdx.x * blockDim.x + threadIdx.x;
    if (gid >= 12288) return;
    int lane = gid & 63, r = (gid >> 6) & 3, ni = (gid >> 8) & 3, mi = (gid >> 10) & 3, h = gid >> 12;
    int i = mi * 16 + ((lane >> 4) << 2) + r;
    int j = ni * 16 + (lane & 15);
    float di = (float)((i >> 3) - (j >> 3));
    float dj = (float)((i & 7) - (j & 7));
    float r0 = (di > 0.f ? 1.f : (di < 0.f ? -1.f : 0.f)) * log1pf(fabsf(di));
    float r1 = (dj > 0.f ? 1.f : (dj < 0.f ? -1.f : 0.f)) * log1pf(fabsf(dj));
    float acc = 0.f;
    for (int t = 0; t < 256; ++t) {
        float u = fmaf(w1[2 * t], r0, fmaf(w1[2 * t + 1], r1, b1[t]));
        u = fmaxf(u, 0.f);
        acc = fmaf(w2[h * 256 + t], u, acc);
    }
    biasF[gid] = acc + b2[h];
}

// ---------------- K0b: weight prep. Whi/Wlo[oo][96] bf16 split (oo = h*96+grp*32+d),
// grp 0=q (QK rows 0..95), 1=k (QK rows 96..191), 2=v (V rows). WTproj[c][96] f32.
__global__ void wtrans_kernel(const float* __restrict__ QK_w, const float* __restrict__ V_w,
                              const float* __restrict__ proj_w,
                              __bf16* __restrict__ Whi, __bf16* __restrict__ Wlo,
                              float* __restrict__ WTproj) {
    int idx = blockIdx.x * blockDim.x + threadIdx.x;
    if (idx < 288 * 96) {
        int oo = idx / 96, c = idx - oo * 96;
        int h = oo / 96, rem = oo - h * 96, grp = rem >> 5, d = rem & 31;
        float w = (grp == 0) ? QK_w[(h * 32 + d) * 96 + c]
                : (grp == 1) ? QK_w[(96 + h * 32 + d) * 96 + c]
                             : V_w[(h * 32 + d) * 96 + c];
        __bf16 hi = (__bf16)w;
        Whi[idx] = hi;
        Wlo[idx] = (__bf16)(w - (float)hi);
    } else if (idx < 288 * 96 + 96 * 96) {
        int rdx = idx - 288 * 96;
        int c = rdx / 96, o = rdx - c * 96;
        WTproj[rdx] = proj_w[o * 96 + c];
    }
}

// ---------------- K1: fused QKV conv + window attention, full MFMA ----------------
// block = 1 window (192 thr, wave = head). LDS 43.5 KB, 2 barriers total.
__global__ __launch_bounds__(192, 2) void fused_qkv_attn(
    const float* __restrict__ x,
    const __bf16* __restrict__ Whi, const __bf16* __restrict__ Wlo,
    const float* __restrict__ QK_b, const float* __restrict__ V_b,
    const float* __restrict__ biasF,
    unsigned short* __restrict__ Vout, float* __restrict__ xr) {
    __shared__ __align__(16) char lds[44544];
    int tid = threadIdx.x;
    int head = tid >> 6;
    int lane = tid & 63;
    int l16 = lane & 15;
    int g8 = (lane >> 4) << 3;
    int g4 = (lane >> 4) << 2;
    int win = blockIdx.x;
    int b = win >> 10;
    int wl = win & 1023;
    int wh = wl >> 5, ww = wl & 31;
    int ph = (wh * 8 + (lane >> 3) + 4) & 255;   // shifted gather (roll cancels on write-back)
    int pw = (ww * 8 + (lane & 7) + 4) & 255;
    int pos = ph * 256 + pw;

    __bf16* Xh = (__bf16*)lds;              // [64 tok][104] (pad) bf16 hi
    __bf16* Xl = (__bf16*)(lds + 13312);    // lo

    // stage x window as bf16 hi/lo, token-major
    const float* xb = x + (size_t)b * 96 * HW;
    for (int idx = tid; idx < 6144; idx += 192) {
        int c = idx >> 6, t = idx & 63;
        int pph = (wh * 8 + (t >> 3) + 4) & 255;
        int ppw = (ww * 8 + (t & 7) + 4) & 255;
        float v = xb[(size_t)c * HW + pph * 256 + ppw];
        __bf16 hi = (__bf16)v;
        Xh[t * 104 + c] = hi;
        Xl[t * 104 + c] = (__bf16)(v - (float)hi);
    }
    __syncthreads();

    // A-fragments (all K-steps) into registers, then Xw LDS is dead
    bf16x8 Ah[4][3], Al[4][3];
#pragma unroll
    for (int mi = 0; mi < 4; ++mi)
#pragma unroll
        for (int ks = 0; ks < 3; ++ks) {
            int off = (mi * 16 + l16) * 104 + ks * 32 + g8;
            Ah[mi][ks] = *(const bf16x8*)(Xh + off);
            Al[mi][ks] = *(const bf16x8*)(Xl + off);
        }
    __syncthreads();   // all waves done with Xw; per-head regions reuse the LDS

    int hU = __builtin_amdgcn_readfirstlane(head);
    char* hb = lds + hU * 14848;
    __bf16* Qr = (__bf16*)hb;              // [64 tok][40] (pad) bf16, (q+bq)*scale
    __bf16* Kr = (__bf16*)(hb + 5120);     // [64 tok][40]
    __bf16* Vt = (__bf16*)(hb + 10240);    // [32 d][72] (pad), v+bv, token-minor
    __bf16* Pr = (__bf16*)hb;              // [64 q][72] probs (overwrites Q,K)
    float*  Xr = (float*)hb;               // [64 tok][36] f32 out (overwrites P)

    // ---- QKV GEMM: 3 output groups (q,k,v), hi/lo 3-pass MFMA ----
#pragma unroll
    for (int grp = 0; grp < 3; ++grp) {
        f32x4 acc[4][2];
#pragma unroll
        for (int mi = 0; mi < 4; ++mi)
#pragma unroll
            for (int ni = 0; ni < 2; ++ni) acc[mi][ni] = (f32x4){0.f, 0.f, 0.f, 0.f};
#pragma unroll
        for (int ks = 0; ks < 3; ++ks)
#pragma unroll
            for (int ni = 0; ni < 2; ++ni) {
                int oo = hU * 96 + grp * 32 + ni * 16 + l16;
                bf16x8 Bh = *(const bf16x8*)(Whi + oo * 96 + ks * 32 + g8);
                bf16x8 Bl = *(const bf16x8*)(Wlo + oo * 96 + ks * 32 + g8);
#pragma unroll
                for (int mi = 0; mi < 4; ++mi) {
                    acc[mi][ni] = __builtin_amdgcn_mfma_f32_16x16x32_bf16(Ah[mi][ks], Bh, acc[mi][ni], 0, 0, 0);
                    acc[mi][ni] = __builtin_amdgcn_mfma_f32_16x16x32_bf16(Al[mi][ks], Bh, acc[mi][ni], 0, 0, 0);
                    acc[mi][ni] = __builtin_amdgcn_mfma_f32_16x16x32_bf16(Ah[mi][ks], Bl, acc[mi][ni], 0, 0, 0);
                }
            }
        // repack C-frags -> per-head LDS (bias folded; Q also pre-scaled)
#pragma unroll
        for (int ni = 0; ni < 2; ++ni) {
            int d = ni * 16 + l16;
            float bias = (grp == 0) ? QK_b[hU * 32 + d]
                       : (grp == 1) ? QK_b[96 + hU * 32 + d] : V_b[hU * 32 + d];
#pragma unroll
            for (int mi = 0; mi < 4; ++mi)
#pragma unroll
                for (int r = 0; r < 4; ++r) {
                    int row = mi * 16 + g4 + r;
                    float val = acc[mi][ni][r] + bias;
                    if (grp == 0)      Qr[row * 40 + d] = (__bf16)(val * SCALE_Q);
                    else if (grp == 1) Kr[row * 40 + d] = (__bf16)val;
                    else               Vt[d * 72 + row] = (__bf16)val;
                }
        }
    }

    // V (biased, bf16) to global for the depthwise conv; lane = token
#pragma unroll
    for (int d = 0; d < 32; ++d)
        Vout[(size_t)(b * 96 + hU * 32 + d) * HW + pos] = ((const unsigned short*)Vt)[d * 72 + lane];

    // ---- QK^T (bf16 MFMA, K=32 one step) ----
    bf16x8 Qf[4], Kf[4];
#pragma unroll
    for (int mi = 0; mi < 4; ++mi) Qf[mi] = *(const bf16x8*)(Qr + (mi * 16 + l16) * 40 + g8);
#pragma unroll
    for (int ni = 0; ni < 4; ++ni) Kf[ni] = *(const bf16x8*)(Kr + (ni * 16 + l16) * 40 + g8);
    f32x4 sc[4][4];
#pragma unroll
    for (int mi = 0; mi < 4; ++mi)
#pragma unroll
        for (int ni = 0; ni < 4; ++ni) {
            sc[mi][ni] = (f32x4){0.f, 0.f, 0.f, 0.f};
            sc[mi][ni] = __builtin_amdgcn_mfma_f32_16x16x32_bf16(Qf[mi], Kf[ni], sc[mi][ni], 0, 0, 0);
        }

    // ---- bias + Swin mask + softmax (rows live in lane&15-groups) ----
    const float* bF = biasF + hU * 4096;
    bool bhh = (wh == 31), bww = (ww == 31);
    int rc[4];
#pragma unroll
    for (int ni = 0; ni < 4; ++ni) {
        int t = ni * 16 + l16;
        rc[ni] = (bhh ? (((t >> 3) < 4) ? 1 : 2) : 0) * 3 + (bww ? (((t & 7) < 4) ? 1 : 2) : 0);
    }
#pragma unroll
    for (int mi = 0; mi < 4; ++mi)
#pragma unroll
        for (int r = 0; r < 4; ++r) {
            int row = mi * 16 + g4 + r;
            float s0 = sc[mi][0][r] + bF[((mi * 4 + 0) * 4 + r) * 64 + lane];
            float s1 = sc[mi][1][r] + bF[((mi * 4 + 1) * 4 + r) * 64 + lane];
            float s2 = sc[mi][2][r] + bF[((mi * 4 + 2) * 4 + r) * 64 + lane];
            float s3 = sc[mi][3][r] + bF[((mi * 4 + 3) * 4 + r) * 64 + lane];
            if (bhh || bww) {
                int rr = (bhh ? (((row >> 3) < 4) ? 1 : 2) : 0) * 3 +
                         (bww ? (((row & 7) < 4) ? 1 : 2) : 0);
                if (rr != rc[0]) s0 -= 100.f;
                if (rr != rc[1]) s1 -= 100.f;
                if (rr != rc[2]) s2 -= 100.f;
                if (rr != rc[3]) s3 -= 100.f;
            }
            float mm = fmaxf(fmaxf(s0, s1), fmaxf(s2, s3));
            mm = fmaxf(mm, __shfl_xor(mm, 1));
            mm = fmaxf(mm, __shfl_xor(mm, 2));
            mm = fmaxf(mm, __shfl_xor(mm, 4));
            mm = fmaxf(mm, __shfl_xor(mm, 8));
            float e0 = __expf(s0 - mm), e1 = __expf(s1 - mm);
            float e2 = __expf(s2 - mm), e3 = __expf(s3 - mm);
            float sum = e0 + e1 + e2 + e3;
            sum += __shfl_xor(sum, 1);
            sum += __shfl_xor(sum, 2);
            sum += __shfl_xor(sum, 4);
            sum += __shfl_xor(sum, 8);
            float inv = 1.f / sum;
            Pr[row * 72 +  0 + l16] = (__bf16)(e0 * inv);
            Pr[row * 72 + 16 + l16] = (__bf16)(e1 * inv);
            Pr[row * 72 + 32 + l16] = (__bf16)(e2 * inv);
            Pr[row * 72 + 48 + l16] = (__bf16)(e3 * inv);
        }

    // ---- PV (bf16 MFMA, K=64 two steps) ----
    f32x4 po[4][2];
#pragma unroll
    for (int mi = 0; mi < 4; ++mi)
#pragma unroll
        for (int ni = 0; ni < 2; ++ni) po[mi][ni] = (f32x4){0.f, 0.f, 0.f, 0.f};
#pragma unroll
    for (int ks = 0; ks < 2; ++ks) {
        bf16x8 Pf[4], Vf[2];
#pragma unroll
        for (int mi = 0; mi < 4; ++mi) Pf[mi] = *(const bf16x8*)(Pr + (mi * 16 + l16) * 72 + ks * 32 + g8);
#pragma unroll
        for (int ni = 0; ni < 2; ++ni) Vf[ni] = *(const bf16x8*)(Vt + (ni * 16 + l16) * 72 + ks * 32 + g8);
#pragma unroll
        for (int mi = 0; mi < 4; ++mi)
#pragma unroll
            for (int ni = 0; ni < 2; ++ni)
                po[mi][ni] = __builtin_amdgcn_mfma_f32_16x16x32_bf16(Pf[mi], Vf[ni], po[mi][ni], 0, 0, 0);
    }
    // transpose via LDS (overwrites P), then coalesced global write
#pragma unroll
    for (int mi = 0; mi < 4; ++mi)
#pragma unroll
        for (int ni = 0; ni < 2; ++ni)
#pragma unroll
            for (int r = 0; r < 4; ++r)
                Xr[(mi * 16 + g4 + r) * 36 + ni * 16 + l16] = po[mi][ni][r];
    float* xrg = xr + (size_t)(b * 96 + hU * 32) * HW + pos;
#pragma unroll
    for (int c4 = 0; c4 < 8; ++c4) {
        f32x4 v = *(const f32x4*)(Xr + lane * 36 + c4 * 4);
        xrg[(size_t)(c4 * 4 + 0) * HW] = v[0];
        xrg[(size_t)(c4 * 4 + 1) * HW] = v[1];
        xrg[(size_t)(c4 * 4 + 2) * HW] = v[2];
        xrg[(size_t)(c4 * 4 + 3) * HW] = v[3];
    }
}

// ---------------- K2: depthwise 5x5 reflect conv on V(bf16) + xr -> T (in place) ----
__global__ __launch_bounds__(256) void dwconv_kernel(const __hip_bfloat16* __restrict__ V,
                                                     const float* __restrict__ dw_w,
                                                     const float* __restrict__ dw_b,
                                                     float* __restrict__ T) {
    int bx = blockIdx.x;
    int tile = bx & 255;
    int plane = bx >> 8;
    int c = plane % 96;
    int w = (tile & 3) * 64 + (threadIdx.x & 63);
    int h = (tile >> 2) * 4 + (threadIdx.x >> 6);
    const __hip_bfloat16* Vp = V + (size_t)plane * HW;
    const float* wt = dw_w + c * 25;
    float acc = dw_b[c];
#pragma unroll
    for (int dy = -2; dy <= 2; ++dy) {
        int hh = h + dy;
        hh = hh < 0 ? -hh : (hh > 255 ? 510 - hh : hh);
#pragma unroll
        for (int dx = -2; dx <= 2; ++dx) {
            int wp = w + dx;
            wp = wp < 0 ? -wp : (wp > 255 ? 510 - wp : wp);
            acc = fmaf(wt[(dy + 2) * 5 + (dx + 2)], __bfloat162float(Vp[hh * 256 + wp]), acc);
        }
    }
    size_t o = (size_t)plane * HW + h * 256 + w;
    T[o] = acc + T[o];
}

// ---------------- K3: projection 1x1 conv, scalar-pipe weights (in place) ----------
__global__ __launch_bounds__(256) void proj_kernel(const float* __restrict__ x,
                                                   const float* __restrict__ WTp,
                                                   const float* __restrict__ bA,
                                                   float* __restrict__ y) {
    __shared__ float Xs[96][128];
    int bx = blockIdx.x;
    int b  = bx >> 9;
    int m0 = (bx & 511) << 7;
    int tid = threadIdx.x;
    const float* xb = x + (size_t)b * (96 * HW) + m0;
    for (int idx = tid; idx < 96 * 32; idx += 256) {
        int c = idx >> 5, mm = idx & 31;
        float4 vv = *(const float4*)(xb + (size_t)c * HW + mm * 4);
        *(float4*)(&Xs[c][mm * 4]) = vv;
    }
    __syncthreads();
    int m = tid & 127;
    int ohU = __builtin_amdgcn_readfirstlane(tid >> 7);
    for (int oc = 0; oc < 3; ++oc) {
        float acc[16];
#pragma unroll
        for (int u = 0; u < 16; ++u) acc[u] = 0.f;
        const float* wbase = WTp + oc * 32 + ohU * 16;
#pragma unroll 4
        for (int c = 0; c < 96; ++c) {
            float xv = Xs[c][m];
            const float* w = wbase + c * 96;
#pragma unroll
            for (int u = 0; u < 16; ++u) acc[u] = fmaf(w[u], xv, acc[u]);
        }
#pragma unroll
        for (int u = 0; u < 16; ++u) {
            int o = oc * 32 + ohU * 16 + u;
            y[(size_t)b * (96 * HW) + (size_t)o * HW + m0 + m] = acc[u] + bA[o];
        }
    }
}

extern "C" void kernel_launch(void* const* d_in, const int* in_sizes, int n_in,
                              void* d_out, int out_size, void* d_ws, size_t ws_size,
                              hipStream_t stream) {
    const float* x      = (const float*)d_in[0];
    const float* V_w    = (const float*)d_in[1];
    const float* V_b    = (const float*)d_in[2];
    const float* QK_w   = (const float*)d_in[3];
    const float* QK_b   = (const float*)d_in[4];
    const float* proj_w = (const float*)d_in[5];
    const float* proj_b = (const float*)d_in[6];
    const float* dw_w   = (const float*)d_in[7];
    const float* dw_b   = (const float*)d_in[8];
    const float* mw1    = (const float*)d_in[9];
    const float* mb1    = (const float*)d_in[10];
    const float* mw2    = (const float*)d_in[11];
    const float* mb2    = (const float*)d_in[12];
    float* out = (float*)d_out;

    // workspace layout (~96.2 MiB)
    char* ws = (char*)d_ws;
    __hip_bfloat16* Vbuf = (__hip_bfloat16*)ws;                        // 100663296 B
    float*  biasF = (float*)(ws + 100663296);                          // 49152 B
    __bf16* Whi   = (__bf16*)(ws + 100663296 + 49152);                 // 55296 B
    __bf16* Wlo   = (__bf16*)(ws + 100663296 + 49152 + 55296);        // 55296 B
    float*  WTproj= (float*)(ws + 100663296 + 49152 + 55296 + 55296);  // 36864 B

    bias_kernel<<<48, 256, 0, stream>>>(mw1, mb1, mw2, mb2, biasF);
    wtrans_kernel<<<144, 256, 0, stream>>>(QK_w, V_w, proj_w, Whi, Wlo, WTproj);
    fused_qkv_attn<<<8192, 192, 0, stream>>>(x, Whi, Wlo, QK_b, V_b, biasF,
                                             (unsigned short*)Vbuf, out);
    dwconv_kernel<<<196608, 256, 0, stream>>>(Vbuf, dw_w, dw_b, out);
    proj_kernel<<<4096, 256, 0, stream>>>(out, WTproj, proj_b, out);
}

// Round 6
// 856.101 us; speedup vs baseline: 2.7079x; 1.0960x over previous
//
#include <hip/hip_runtime.h>
#include <hip/hip_bf16.h>

#define HW 65536
#define SCALE_Q 0.17677669529663687f

typedef __bf16 bf16x8 __attribute__((ext_vector_type(8)));
typedef float f32x4 __attribute__((ext_vector_type(4)));

// ---------------- K0: rel-pos MLP bias in C-fragment layout ----------------
// biasF[h][mi][ni][r][lane] = bias(h, i=mi*16+(lane>>4)*4+r, j=ni*16+(lane&15))
__global__ void bias_kernel(const float* __restrict__ w1, const float* __restrict__ b1,
                            const float* __restrict__ w2, const float* __restrict__ b2,
                            float* __restrict__ biasF) {
    int gid = blockIdx.x * blockDim.x + threadIdx.x;
    if (gid >= 12288) return;
    int lane = gid & 63, r = (gid >> 6) & 3, ni = (gid >> 8) & 3, mi = (gid >> 10) & 3, h = gid >> 12;
    int i = mi * 16 + ((lane >> 4) << 2) + r;
    int j = ni * 16 + (lane & 15);
    float di = (float)((i >> 3) - (j >> 3));
    float dj = (float)((i & 7) - (j & 7));
    float r0 = (di > 0.f ? 1.f : (di < 0.f ? -1.f : 0.f)) * log1pf(fabsf(di));
    float r1 = (dj > 0.f ? 1.f : (dj < 0.f ? -1.f : 0.f)) * log1pf(fabsf(dj));
    float acc = 0.f;
    for (int t = 0; t < 256; ++t) {
        float u = fmaf(w1[2 * t], r0, fmaf(w1[2 * t + 1], r1, b1[t]));
        u = fmaxf(u, 0.f);
        acc = fmaf(w2[h * 256 + t], u, acc);
    }
    biasF[gid] = acc + b2[h];
}

// ---------------- K0b: weight prep (bf16 hi/lo of W rows, proj transpose) ----------
__global__ void wtrans_kernel(const float* __restrict__ QK_w, const float* __restrict__ V_w,
                              const float* __restrict__ proj_w,
                              __bf16* __restrict__ Whi, __bf16* __restrict__ Wlo,
                              float* __restrict__ WTproj) {
    int idx = blockIdx.x * blockDim.x + threadIdx.x;
    if (idx < 288 * 96) {
        int oo = idx / 96, c = idx - oo * 96;
        int h = oo / 96, rem = oo - h * 96, grp = rem >> 5, d = rem & 31;
        float w = (grp == 0) ? QK_w[(h * 32 + d) * 96 + c]
                : (grp == 1) ? QK_w[(96 + h * 32 + d) * 96 + c]
                             : V_w[(h * 32 + d) * 96 + c];
        __bf16 hi = (__bf16)w;
        Whi[idx] = hi;
        Wlo[idx] = (__bf16)(w - (float)hi);
    } else if (idx < 288 * 96 + 96 * 96) {
        int rdx = idx - 288 * 96;
        int c = rdx / 96, o = rdx - c * 96;
        WTproj[rdx] = proj_w[o * 96 + c];
    }
}

// ---------------- K1: fused QKV conv + window attention, MFMA, 29.25 KB LDS ----------
// block = 1 window (192 thr, wave = head). Per-head 9.75 KB slab time-shared:
// Q -> K -> P(ks0) -> P(ks1) in one [64][40] region; Vt [32][72] persists; Xr overlays all.
__global__ __launch_bounds__(192, 4) void fused_qkv_attn(
    const float* __restrict__ x,
    const __bf16* __restrict__ Whi, const __bf16* __restrict__ Wlo,
    const float* __restrict__ QK_b, const float* __restrict__ V_b,
    const float* __restrict__ biasF,
    unsigned short* __restrict__ Vout, float* __restrict__ xr) {
    __shared__ __align__(16) char lds[29952];
    int tid = threadIdx.x;
    int head = tid >> 6;
    int lane = tid & 63;
    int l16 = lane & 15;
    int g8 = (lane >> 4) << 3;
    int g4 = (lane >> 4) << 2;
    int win = blockIdx.x;
    int b = win >> 10;
    int wl = win & 1023;
    int wh = wl >> 5, ww = wl & 31;
    int ph = (wh * 8 + (lane >> 3) + 4) & 255;   // shifted gather (roll cancels on write-back)
    int pw = (ww * 8 + (lane & 7) + 4) & 255;
    int pos = ph * 256 + pw;

    __bf16* Xh = (__bf16*)lds;   // [64 tok][104] bf16 (hi only)
    const float* xb = x + (size_t)b * 96 * HW;
    for (int idx = tid; idx < 6144; idx += 192) {
        int c = idx >> 6, t = idx & 63;
        int pph = (wh * 8 + (t >> 3) + 4) & 255;
        int ppw = (ww * 8 + (t & 7) + 4) & 255;
        Xh[t * 104 + c] = (__bf16)xb[(size_t)c * HW + pph * 256 + ppw];
    }
    __syncthreads();

    // A-fragments for all K-steps -> registers; then staging LDS is dead
    bf16x8 Ah[4][3];
#pragma unroll
    for (int mi = 0; mi < 4; ++mi)
#pragma unroll
        for (int ks = 0; ks < 3; ++ks)
            Ah[mi][ks] = *(const bf16x8*)(Xh + (mi * 16 + l16) * 104 + ks * 32 + g8);
    __syncthreads();   // all waves done with Xh; per-head slabs reuse the LDS

    int hU = __builtin_amdgcn_readfirstlane(head);
    char* hb = lds + hU * 9984;
    __bf16* slab = (__bf16*)hb;            // [64][40] bf16: Q, then K, then P halves
    __bf16* Vt   = (__bf16*)(hb + 5120);   // [32 d][72 tok] bf16
    float*  Xr   = (float*)hb;             // [64][36] f32 (final overlay)

    bf16x8 Qf[4], Kf[4];
    // ---- Q (1-pass) ----
    {
        f32x4 acc[4][2];
#pragma unroll
        for (int mi = 0; mi < 4; ++mi)
#pragma unroll
            for (int ni = 0; ni < 2; ++ni) acc[mi][ni] = (f32x4){0.f, 0.f, 0.f, 0.f};
#pragma unroll
        for (int ks = 0; ks < 3; ++ks)
#pragma unroll
            for (int ni = 0; ni < 2; ++ni) {
                bf16x8 Bh = *(const bf16x8*)(Whi + (hU * 96 + ni * 16 + l16) * 96 + ks * 32 + g8);
#pragma unroll
                for (int mi = 0; mi < 4; ++mi)
                    acc[mi][ni] = __builtin_amdgcn_mfma_f32_16x16x32_bf16(Ah[mi][ks], Bh, acc[mi][ni], 0, 0, 0);
            }
#pragma unroll
        for (int ni = 0; ni < 2; ++ni) {
            float bias = QK_b[hU * 32 + ni * 16 + l16];
#pragma unroll
            for (int mi = 0; mi < 4; ++mi)
#pragma unroll
                for (int r = 0; r < 4; ++r)
                    slab[(mi * 16 + g4 + r) * 40 + ni * 16 + l16] = (__bf16)((acc[mi][ni][r] + bias) * SCALE_Q);
        }
#pragma unroll
        for (int mi = 0; mi < 4; ++mi) Qf[mi] = *(const bf16x8*)(slab + (mi * 16 + l16) * 40 + g8);
    }
    // ---- K (1-pass, reuses slab) ----
    {
        f32x4 acc[4][2];
#pragma unroll
        for (int mi = 0; mi < 4; ++mi)
#pragma unroll
            for (int ni = 0; ni < 2; ++ni) acc[mi][ni] = (f32x4){0.f, 0.f, 0.f, 0.f};
#pragma unroll
        for (int ks = 0; ks < 3; ++ks)
#pragma unroll
            for (int ni = 0; ni < 2; ++ni) {
                bf16x8 Bh = *(const bf16x8*)(Whi + (hU * 96 + 32 + ni * 16 + l16) * 96 + ks * 32 + g8);
#pragma unroll
                for (int mi = 0; mi < 4; ++mi)
                    acc[mi][ni] = __builtin_amdgcn_mfma_f32_16x16x32_bf16(Ah[mi][ks], Bh, acc[mi][ni], 0, 0, 0);
            }
#pragma unroll
        for (int ni = 0; ni < 2; ++ni) {
            float bias = QK_b[96 + hU * 32 + ni * 16 + l16];
#pragma unroll
            for (int mi = 0; mi < 4; ++mi)
#pragma unroll
                for (int r = 0; r < 4; ++r)
                    slab[(mi * 16 + g4 + r) * 40 + ni * 16 + l16] = (__bf16)(acc[mi][ni][r] + bias);
        }
#pragma unroll
        for (int mi = 0; mi < 4; ++mi) Kf[mi] = *(const bf16x8*)(slab + (mi * 16 + l16) * 40 + g8);
    }
    // ---- V (2-pass: Xh*Whi + Xh*Wlo) ----
    {
        f32x4 acc[4][2];
#pragma unroll
        for (int mi = 0; mi < 4; ++mi)
#pragma unroll
            for (int ni = 0; ni < 2; ++ni) acc[mi][ni] = (f32x4){0.f, 0.f, 0.f, 0.f};
#pragma unroll
        for (int ks = 0; ks < 3; ++ks)
#pragma unroll
            for (int ni = 0; ni < 2; ++ni) {
                int oo = (hU * 96 + 64 + ni * 16 + l16) * 96 + ks * 32 + g8;
                bf16x8 Bh = *(const bf16x8*)(Whi + oo);
                bf16x8 Bl = *(const bf16x8*)(Wlo + oo);
#pragma unroll
                for (int mi = 0; mi < 4; ++mi) {
                    acc[mi][ni] = __builtin_amdgcn_mfma_f32_16x16x32_bf16(Ah[mi][ks], Bh, acc[mi][ni], 0, 0, 0);
                    acc[mi][ni] = __builtin_amdgcn_mfma_f32_16x16x32_bf16(Ah[mi][ks], Bl, acc[mi][ni], 0, 0, 0);
                }
            }
#pragma unroll
        for (int ni = 0; ni < 2; ++ni) {
            float bias = V_b[hU * 32 + ni * 16 + l16];
#pragma unroll
            for (int mi = 0; mi < 4; ++mi)
#pragma unroll
                for (int r = 0; r < 4; ++r)
                    Vt[(ni * 16 + l16) * 72 + mi * 16 + g4 + r] = (__bf16)(acc[mi][ni][r] + bias);
        }
    }
    // V (biased, bf16) to global for the depthwise conv; lane = token
#pragma unroll
    for (int d = 0; d < 32; ++d)
        Vout[(size_t)(b * 96 + hU * 32 + d) * HW + pos] = ((const unsigned short*)Vt)[d * 72 + lane];

    // ---- QK^T ----
    f32x4 sc[4][4];
#pragma unroll
    for (int mi = 0; mi < 4; ++mi)
#pragma unroll
        for (int ni = 0; ni < 4; ++ni) {
            sc[mi][ni] = (f32x4){0.f, 0.f, 0.f, 0.f};
            sc[mi][ni] = __builtin_amdgcn_mfma_f32_16x16x32_bf16(Qf[mi], Kf[ni], sc[mi][ni], 0, 0, 0);
        }

    // ---- bias + Swin mask + softmax (P stored back into sc) ----
    const float* bF = biasF + hU * 4096;
    bool bhh = (wh == 31), bww = (ww == 31);
    int rc[4];
#pragma unroll
    for (int ni = 0; ni < 4; ++ni) {
        int t = ni * 16 + l16;
        rc[ni] = (bhh ? (((t >> 3) < 4) ? 1 : 2) : 0) * 3 + (bww ? (((t & 7) < 4) ? 1 : 2) : 0);
    }
#pragma unroll
    for (int mi = 0; mi < 4; ++mi)
#pragma unroll
        for (int r = 0; r < 4; ++r) {
            int row = mi * 16 + g4 + r;
            float s0 = sc[mi][0][r] + bF[((mi * 4 + 0) * 4 + r) * 64 + lane];
            float s1 = sc[mi][1][r] + bF[((mi * 4 + 1) * 4 + r) * 64 + lane];
            float s2 = sc[mi][2][r] + bF[((mi * 4 + 2) * 4 + r) * 64 + lane];
            float s3 = sc[mi][3][r] + bF[((mi * 4 + 3) * 4 + r) * 64 + lane];
            if (bhh || bww) {
                int rr = (bhh ? (((row >> 3) < 4) ? 1 : 2) : 0) * 3 +
                         (bww ? (((row & 7) < 4) ? 1 : 2) : 0);
                if (rr != rc[0]) s0 -= 100.f;
                if (rr != rc[1]) s1 -= 100.f;
                if (rr != rc[2]) s2 -= 100.f;
                if (rr != rc[3]) s3 -= 100.f;
            }
            float mm = fmaxf(fmaxf(s0, s1), fmaxf(s2, s3));
            mm = fmaxf(mm, __shfl_xor(mm, 1));
            mm = fmaxf(mm, __shfl_xor(mm, 2));
            mm = fmaxf(mm, __shfl_xor(mm, 4));
            mm = fmaxf(mm, __shfl_xor(mm, 8));
            float e0 = __expf(s0 - mm), e1 = __expf(s1 - mm);
            float e2 = __expf(s2 - mm), e3 = __expf(s3 - mm);
            float sum = e0 + e1 + e2 + e3;
            sum += __shfl_xor(sum, 1);
            sum += __shfl_xor(sum, 2);
            sum += __shfl_xor(sum, 4);
            sum += __shfl_xor(sum, 8);
            float inv = 1.f / sum;
            sc[mi][0][r] = e0 * inv;
            sc[mi][1][r] = e1 * inv;
            sc[mi][2][r] = e2 * inv;
            sc[mi][3][r] = e3 * inv;
        }

    // ---- PV: two K-halves, P staged through the slab ----
    f32x4 po[4][2];
#pragma unroll
    for (int mi = 0; mi < 4; ++mi)
#pragma unroll
        for (int ni = 0; ni < 2; ++ni) po[mi][ni] = (f32x4){0.f, 0.f, 0.f, 0.f};
#pragma unroll
    for (int ks = 0; ks < 2; ++ks) {
#pragma unroll
        for (int mi = 0; mi < 4; ++mi)
#pragma unroll
            for (int r = 0; r < 4; ++r) {
                int row = mi * 16 + g4 + r;
                slab[row * 40 + l16]      = (__bf16)sc[mi][ks * 2 + 0][r];
                slab[row * 40 + 16 + l16] = (__bf16)sc[mi][ks * 2 + 1][r];
            }
        bf16x8 Vf[2], Pf;
#pragma unroll
        for (int ni = 0; ni < 2; ++ni)
            Vf[ni] = *(const bf16x8*)(Vt + (ni * 16 + l16) * 72 + ks * 32 + g8);
#pragma unroll
        for (int mi = 0; mi < 4; ++mi) {
            Pf = *(const bf16x8*)(slab + (mi * 16 + l16) * 40 + g8);
#pragma unroll
            for (int ni = 0; ni < 2; ++ni)
                po[mi][ni] = __builtin_amdgcn_mfma_f32_16x16x32_bf16(Pf, Vf[ni], po[mi][ni], 0, 0, 0);
        }
    }
    // transpose via LDS (overlays slab+Vt), coalesced global write
#pragma unroll
    for (int mi = 0; mi < 4; ++mi)
#pragma unroll
        for (int ni = 0; ni < 2; ++ni)
#pragma unroll
            for (int r = 0; r < 4; ++r)
                Xr[(mi * 16 + g4 + r) * 36 + ni * 16 + l16] = po[mi][ni][r];
    float* xrg = xr + (size_t)(b * 96 + hU * 32) * HW + pos;
#pragma unroll
    for (int c4 = 0; c4 < 8; ++c4) {
        f32x4 v = *(const f32x4*)(Xr + lane * 36 + c4 * 4);
        xrg[(size_t)(c4 * 4 + 0) * HW] = v[0];
        xrg[(size_t)(c4 * 4 + 1) * HW] = v[1];
        xrg[(size_t)(c4 * 4 + 2) * HW] = v[2];
        xrg[(size_t)(c4 * 4 + 3) * HW] = v[3];
    }
}

// ---------------- K2: depthwise 5x5 reflect conv, 8 outputs/thread -----------------
__global__ __launch_bounds__(256) void dwconv_kernel(const __hip_bfloat16* __restrict__ V,
                                                     const float* __restrict__ dw_w,
                                                     const float* __restrict__ dw_b,
                                                     float* __restrict__ T) {
    int bx = blockIdx.x;
    int strip = bx & 31;           // 32 strips of 8 rows per plane
    int plane = bx >> 5;           // b*96 + c
    int c = plane % 96;
    int r = threadIdx.x >> 5;
    int jq = (threadIdx.x & 31) << 3;   // 8 outputs per thread along w
    int h = strip * 8 + r;
    const __hip_bfloat16* Vp = V + (size_t)plane * HW;
    const float* wt = dw_w + c * 25;
    float acc[8];
    float bias = dw_b[c];
#pragma unroll
    for (int i = 0; i < 8; ++i) acc[i] = bias;
    bool fast = (jq >= 8 && jq <= 240);
#pragma unroll
    for (int dy = -2; dy <= 2; ++dy) {
        int hh = h + dy;
        hh = hh < 0 ? -hh : (hh > 255 ? 510 - hh : hh);
        const __hip_bfloat16* row = Vp + hh * 256;
        float xv[16];   // cols jq-4 .. jq+11
        if (fast) {
            const ushort4* rp = (const ushort4*)(row + jq - 4);
#pragma unroll
            for (int g = 0; g < 4; ++g) {
                ushort4 u = rp[g];
                xv[g * 4 + 0] = __bfloat162float(*(const __hip_bfloat16*)&u.x);
                xv[g * 4 + 1] = __bfloat162float(*(const __hip_bfloat16*)&u.y);
                xv[g * 4 + 2] = __bfloat162float(*(const __hip_bfloat16*)&u.z);
                xv[g * 4 + 3] = __bfloat162float(*(const __hip_bfloat16*)&u.w);
            }
        } else {
#pragma unroll
            for (int idx = 0; idx < 16; ++idx) {
                int col = jq - 4 + idx;
                col = col < 0 ? -col : (col > 255 ? 510 - col : col);
                xv[idx] = __bfloat162float(row[col]);
            }
        }
        const float* w5 = wt + (dy + 2) * 5;
#pragma unroll
        for (int dx = 0; dx < 5; ++dx) {
            float wv = w5[dx];
#pragma unroll
            for (int i = 0; i < 8; ++i)
                acc[i] = fmaf(wv, xv[i + dx + 2], acc[i]);
        }
    }
    size_t o = (size_t)plane * HW + h * 256 + jq;
    float4 t0 = *(const float4*)(T + o);
    float4 t1 = *(const float4*)(T + o + 4);
    t0.x += acc[0]; t0.y += acc[1]; t0.z += acc[2]; t0.w += acc[3];
    t1.x += acc[4]; t1.y += acc[5]; t1.z += acc[6]; t1.w += acc[7];
    *(float4*)(T + o) = t0;
    *(float4*)(T + o + 4) = t1;
}

// ---------------- K3: projection 1x1 conv, scalar-pipe weights (in place) ----------
__global__ __launch_bounds__(256) void proj_kernel(const float* __restrict__ x,
                                                   const float* __restrict__ WTp,
                                                   const float* __restrict__ bA,
                                                   float* __restrict__ y) {
    __shared__ float Xs[96][128];
    int bx = blockIdx.x;
    int b  = bx >> 9;
    int m0 = (bx & 511) << 7;
    int tid = threadIdx.x;
    const float* xb = x + (size_t)b * (96 * HW) + m0;
    for (int idx = tid; idx < 96 * 32; idx += 256) {
        int c = idx >> 5, mm = idx & 31;
        float4 vv = *(const float4*)(xb + (size_t)c * HW + mm * 4);
        *(float4*)(&Xs[c][mm * 4]) = vv;
    }
    __syncthreads();
    int m = tid & 127;
    int ohU = __builtin_amdgcn_readfirstlane(tid >> 7);
    for (int oc = 0; oc < 3; ++oc) {
        float acc[16];
#pragma unroll
        for (int u = 0; u < 16; ++u) acc[u] = 0.f;
        const float* wbase = WTp + oc * 32 + ohU * 16;
#pragma unroll 4
        for (int c = 0; c < 96; ++c) {
            float xv = Xs[c][m];
            const float* w = wbase + c * 96;
#pragma unroll
            for (int u = 0; u < 16; ++u) acc[u] = fmaf(w[u], xv, acc[u]);
        }
#pragma unroll
        for (int u = 0; u < 16; ++u) {
            int o = oc * 32 + ohU * 16 + u;
            y[(size_t)b * (96 * HW) + (size_t)o * HW + m0 + m] = acc[u] + bA[o];
        }
    }
}

extern "C" void kernel_launch(void* const* d_in, const int* in_sizes, int n_in,
                              void* d_out, int out_size, void* d_ws, size_t ws_size,
                              hipStream_t stream) {
    const float* x      = (const float*)d_in[0];
    const float* V_w    = (const float*)d_in[1];
    const float* V_b    = (const float*)d_in[2];
    const float* QK_w   = (const float*)d_in[3];
    const float* QK_b   = (const float*)d_in[4];
    const float* proj_w = (const float*)d_in[5];
    const float* proj_b = (const float*)d_in[6];
    const float* dw_w   = (const float*)d_in[7];
    const float* dw_b   = (const float*)d_in[8];
    const float* mw1    = (const float*)d_in[9];
    const float* mb1    = (const float*)d_in[10];
    const float* mw2    = (const float*)d_in[11];
    const float* mb2    = (const float*)d_in[12];
    float* out = (float*)d_out;

    // workspace layout (~96.2 MiB)
    char* ws = (char*)d_ws;
    __hip_bfloat16* Vbuf = (__hip_bfloat16*)ws;                        // 100663296 B
    float*  biasF = (float*)(ws + 100663296);                          // 49152 B
    __bf16* Whi   = (__bf16*)(ws + 100663296 + 49152);                 // 55296 B
    __bf16* Wlo   = (__bf16*)(ws + 100663296 + 49152 + 55296);        // 55296 B
    float*  WTproj= (float*)(ws + 100663296 + 49152 + 55296 + 55296);  // 36864 B

    bias_kernel<<<48, 256, 0, stream>>>(mw1, mb1, mw2, mb2, biasF);
    wtrans_kernel<<<144, 256, 0, stream>>>(QK_w, V_w, proj_w, Whi, Wlo, WTproj);
    fused_qkv_attn<<<8192, 192, 0, stream>>>(x, Whi, Wlo, QK_b, V_b, biasF,
                                             (unsigned short*)Vbuf, out);
    dwconv_kernel<<<24576, 256, 0, stream>>>(Vbuf, dw_w, dw_b, out);
    proj_kernel<<<4096, 256, 0, stream>>>(out, WTproj, proj_b, out);
}

// Round 7
// 786.489 us; speedup vs baseline: 2.9476x; 1.0885x over previous
//
#include <hip/hip_runtime.h>
#include <hip/hip_bf16.h>

#define HW 65536
#define SCALE_Q 0.17677669529663687f

typedef __bf16 bf16x8 __attribute__((ext_vector_type(8)));
typedef float f32x4 __attribute__((ext_vector_type(4)));

// ---------------- K0: rel-pos MLP bias in C-fragment layout ----------------
__global__ void bias_kernel(const float* __restrict__ w1, const float* __restrict__ b1,
                            const float* __restrict__ w2, const float* __restrict__ b2,
                            float* __restrict__ biasF) {
    int gid = blockIdx.x * blockDim.x + threadIdx.x;
    if (gid >= 12288) return;
    int lane = gid & 63, r = (gid >> 6) & 3, ni = (gid >> 8) & 3, mi = (gid >> 10) & 3, h = gid >> 12;
    int i = mi * 16 + ((lane >> 4) << 2) + r;
    int j = ni * 16 + (lane & 15);
    float di = (float)((i >> 3) - (j >> 3));
    float dj = (float)((i & 7) - (j & 7));
    float r0 = (di > 0.f ? 1.f : (di < 0.f ? -1.f : 0.f)) * log1pf(fabsf(di));
    float r1 = (dj > 0.f ? 1.f : (dj < 0.f ? -1.f : 0.f)) * log1pf(fabsf(dj));
    float acc = 0.f;
    for (int t = 0; t < 256; ++t) {
        float u = fmaf(w1[2 * t], r0, fmaf(w1[2 * t + 1], r1, b1[t]));
        u = fmaxf(u, 0.f);
        acc = fmaf(w2[h * 256 + t], u, acc);
    }
    biasF[gid] = acc + b2[h];
}

// ---------------- K0b: weight prep (bf16 hi/lo of W rows, proj transpose) ----------
__global__ void wtrans_kernel(const float* __restrict__ QK_w, const float* __restrict__ V_w,
                              const float* __restrict__ proj_w,
                              __bf16* __restrict__ Whi, __bf16* __restrict__ Wlo,
                              float* __restrict__ WTproj) {
    int idx = blockIdx.x * blockDim.x + threadIdx.x;
    if (idx < 288 * 96) {
        int oo = idx / 96, c = idx - oo * 96;
        int h = oo / 96, rem = oo - h * 96, grp = rem >> 5, d = rem & 31;
        float w = (grp == 0) ? QK_w[(h * 32 + d) * 96 + c]
                : (grp == 1) ? QK_w[(96 + h * 32 + d) * 96 + c]
                             : V_w[(h * 32 + d) * 96 + c];
        __bf16 hi = (__bf16)w;
        Whi[idx] = hi;
        Wlo[idx] = (__bf16)(w - (float)hi);
    } else if (idx < 288 * 96 + 96 * 96) {
        int rdx = idx - 288 * 96;
        int c = rdx / 96, o = rdx - c * 96;
        WTproj[rdx] = proj_w[o * 96 + c];
    }
}

// ---------------- K1: fused QKV conv + window attention ----------------
// block = strip of 4 adjacent windows (256 thr, wave = window, 3 heads looped).
// V -> SHIFTED planar bf16 (full-line block writes); xr -> original planar f32.
__global__ __launch_bounds__(256, 3) void fused_qkv_attn(
    const float* __restrict__ x,
    const __bf16* __restrict__ Whi, const __bf16* __restrict__ Wlo,
    const float* __restrict__ QK_b, const float* __restrict__ V_b,
    const float* __restrict__ biasF,
    unsigned short* __restrict__ Vout, float* __restrict__ xr) {
    __shared__ __align__(16) char lds[53376];   // staging 4x6672 bf16 (overlaid by 4x9984 slabs)
    int tid = threadIdx.x;
    int w4 = tid >> 6;
    int lane = tid & 63;
    int l16 = lane & 15;
    int g8 = (lane >> 4) << 3;
    int g4 = (lane >> 4) << 2;
    int bx0 = blockIdx.x;
    int bxs = (bx0 & 7) * 256 + (bx0 >> 3);   // XCD-contiguous swizzle (2048 % 8 == 0)
    int b = bxs >> 8;
    int wh = (bxs >> 3) & 31;
    int ww0 = (bxs & 7) << 2;
    int wh8 = wh << 3;
    int wb8 = ww0 << 3;
    int ww = ww0 + w4;
    int ti = lane >> 3, tj = lane & 7;
    int ph = (wh8 + ti + 4) & 255;
    int pw = ((ww << 3) + tj + 4) & 255;
    int pos   = ph * 256 + pw;                          // original planar (xr)
    int pos_s = (wh8 + ti) * 256 + (ww << 3) + tj;      // shifted planar (V)

    // stage x strip: 4 windows, token-major bf16, window stride 6672 elem (bank-spread)
    __bf16* Xh = (__bf16*)lds;
    const float* xb = x + (size_t)b * 96 * HW;
    for (int idx = tid; idx < 24576; idx += 256) {
        int c = idx >> 8, r = (idx >> 5) & 7, col = idx & 31;
        int pph = (wh8 + r + 4) & 255;
        int ppw = (wb8 + col + 4) & 255;
        Xh[(col >> 3) * 6672 + (r * 8 + (col & 7)) * 104 + c] =
            (__bf16)xb[(size_t)c * HW + pph * 256 + ppw];
    }
    __syncthreads();

    // A-fragments (head-independent) -> registers
    bf16x8 Ah[4][3];
    const __bf16* Xw = Xh + w4 * 6672;
#pragma unroll
    for (int mi = 0; mi < 4; ++mi)
#pragma unroll
        for (int ks = 0; ks < 3; ++ks)
            Ah[mi][ks] = *(const bf16x8*)(Xw + (mi * 16 + l16) * 104 + ks * 32 + g8);
    __syncthreads();   // staging dead; per-wave slabs overlay it

    char* hb = lds + w4 * 9984;
    __bf16* slab = (__bf16*)hb;            // [64][40] bf16: Q, K, P stages
    __bf16* Vt   = (__bf16*)(hb + 5120);   // [32 d][72 tok]
    float*  Xr   = (float*)hb;             // [64][36] f32 overlay

    bool bhh = (wh == 31), bww = (ww == 31);
    int rc[4];
#pragma unroll
    for (int ni = 0; ni < 4; ++ni) {
        int t = ni * 16 + l16;
        rc[ni] = (bhh ? (((t >> 3) < 4) ? 1 : 2) : 0) * 3 + (bww ? (((t & 7) < 4) ? 1 : 2) : 0);
    }

#pragma unroll 1
    for (int h = 0; h < 3; ++h) {
        bf16x8 Qf[4], Kf[4];
        // ---- Q (1-pass) ----
        {
            f32x4 acc[4][2];
#pragma unroll
            for (int mi = 0; mi < 4; ++mi)
#pragma unroll
                for (int ni = 0; ni < 2; ++ni) acc[mi][ni] = (f32x4){0.f, 0.f, 0.f, 0.f};
#pragma unroll
            for (int ks = 0; ks < 3; ++ks)
#pragma unroll
                for (int ni = 0; ni < 2; ++ni) {
                    bf16x8 Bh = *(const bf16x8*)(Whi + (h * 96 + ni * 16 + l16) * 96 + ks * 32 + g8);
#pragma unroll
                    for (int mi = 0; mi < 4; ++mi)
                        acc[mi][ni] = __builtin_amdgcn_mfma_f32_16x16x32_bf16(Ah[mi][ks], Bh, acc[mi][ni], 0, 0, 0);
                }
#pragma unroll
            for (int ni = 0; ni < 2; ++ni) {
                float bias = QK_b[h * 32 + ni * 16 + l16];
#pragma unroll
                for (int mi = 0; mi < 4; ++mi)
#pragma unroll
                    for (int r = 0; r < 4; ++r)
                        slab[(mi * 16 + g4 + r) * 40 + ni * 16 + l16] = (__bf16)((acc[mi][ni][r] + bias) * SCALE_Q);
            }
#pragma unroll
            for (int mi = 0; mi < 4; ++mi) Qf[mi] = *(const bf16x8*)(slab + (mi * 16 + l16) * 40 + g8);
        }
        // ---- K (1-pass) ----
        {
            f32x4 acc[4][2];
#pragma unroll
            for (int mi = 0; mi < 4; ++mi)
#pragma unroll
                for (int ni = 0; ni < 2; ++ni) acc[mi][ni] = (f32x4){0.f, 0.f, 0.f, 0.f};
#pragma unroll
            for (int ks = 0; ks < 3; ++ks)
#pragma unroll
                for (int ni = 0; ni < 2; ++ni) {
                    bf16x8 Bh = *(const bf16x8*)(Whi + (h * 96 + 32 + ni * 16 + l16) * 96 + ks * 32 + g8);
#pragma unroll
                    for (int mi = 0; mi < 4; ++mi)
                        acc[mi][ni] = __builtin_amdgcn_mfma_f32_16x16x32_bf16(Ah[mi][ks], Bh, acc[mi][ni], 0, 0, 0);
                }
#pragma unroll
            for (int ni = 0; ni < 2; ++ni) {
                float bias = QK_b[96 + h * 32 + ni * 16 + l16];
#pragma unroll
                for (int mi = 0; mi < 4; ++mi)
#pragma unroll
                    for (int r = 0; r < 4; ++r)
                        slab[(mi * 16 + g4 + r) * 40 + ni * 16 + l16] = (__bf16)(acc[mi][ni][r] + bias);
            }
#pragma unroll
            for (int mi = 0; mi < 4; ++mi) Kf[mi] = *(const bf16x8*)(slab + (mi * 16 + l16) * 40 + g8);
        }
        // ---- V (2-pass hi/lo) ----
        {
            f32x4 acc[4][2];
#pragma unroll
            for (int mi = 0; mi < 4; ++mi)
#pragma unroll
                for (int ni = 0; ni < 2; ++ni) acc[mi][ni] = (f32x4){0.f, 0.f, 0.f, 0.f};
#pragma unroll
            for (int ks = 0; ks < 3; ++ks)
#pragma unroll
                for (int ni = 0; ni < 2; ++ni) {
                    int oo = (h * 96 + 64 + ni * 16 + l16) * 96 + ks * 32 + g8;
                    bf16x8 Bh = *(const bf16x8*)(Whi + oo);
                    bf16x8 Bl = *(const bf16x8*)(Wlo + oo);
#pragma unroll
                    for (int mi = 0; mi < 4; ++mi) {
                        acc[mi][ni] = __builtin_amdgcn_mfma_f32_16x16x32_bf16(Ah[mi][ks], Bh, acc[mi][ni], 0, 0, 0);
                        acc[mi][ni] = __builtin_amdgcn_mfma_f32_16x16x32_bf16(Ah[mi][ks], Bl, acc[mi][ni], 0, 0, 0);
                    }
                }
#pragma unroll
            for (int ni = 0; ni < 2; ++ni) {
                float bias = V_b[h * 32 + ni * 16 + l16];
#pragma unroll
                for (int mi = 0; mi < 4; ++mi)
#pragma unroll
                    for (int r = 0; r < 4; ++r)
                        Vt[(ni * 16 + l16) * 72 + mi * 16 + g4 + r] = (__bf16)(acc[mi][ni][r] + bias);
            }
        }
        // V (shifted planar) to global
#pragma unroll
        for (int d = 0; d < 32; ++d)
            Vout[(size_t)(b * 96 + h * 32 + d) * HW + pos_s] = ((const unsigned short*)Vt)[d * 72 + lane];

        // ---- QK^T ----
        f32x4 sc[4][4];
#pragma unroll
        for (int mi = 0; mi < 4; ++mi)
#pragma unroll
            for (int ni = 0; ni < 4; ++ni) {
                sc[mi][ni] = (f32x4){0.f, 0.f, 0.f, 0.f};
                sc[mi][ni] = __builtin_amdgcn_mfma_f32_16x16x32_bf16(Qf[mi], Kf[ni], sc[mi][ni], 0, 0, 0);
            }
        // ---- bias + mask + softmax ----
        const float* bF = biasF + h * 4096;
#pragma unroll
        for (int mi = 0; mi < 4; ++mi)
#pragma unroll
            for (int r = 0; r < 4; ++r) {
                int row = mi * 16 + g4 + r;
                float s0 = sc[mi][0][r] + bF[((mi * 4 + 0) * 4 + r) * 64 + lane];
                float s1 = sc[mi][1][r] + bF[((mi * 4 + 1) * 4 + r) * 64 + lane];
                float s2 = sc[mi][2][r] + bF[((mi * 4 + 2) * 4 + r) * 64 + lane];
                float s3 = sc[mi][3][r] + bF[((mi * 4 + 3) * 4 + r) * 64 + lane];
                if (bhh || bww) {
                    int rr = (bhh ? (((row >> 3) < 4) ? 1 : 2) : 0) * 3 +
                             (bww ? (((row & 7) < 4) ? 1 : 2) : 0);
                    if (rr != rc[0]) s0 -= 100.f;
                    if (rr != rc[1]) s1 -= 100.f;
                    if (rr != rc[2]) s2 -= 100.f;
                    if (rr != rc[3]) s3 -= 100.f;
                }
                float mm = fmaxf(fmaxf(s0, s1), fmaxf(s2, s3));
                mm = fmaxf(mm, __shfl_xor(mm, 1));
                mm = fmaxf(mm, __shfl_xor(mm, 2));
                mm = fmaxf(mm, __shfl_xor(mm, 4));
                mm = fmaxf(mm, __shfl_xor(mm, 8));
                float e0 = __expf(s0 - mm), e1 = __expf(s1 - mm);
                float e2 = __expf(s2 - mm), e3 = __expf(s3 - mm);
                float sum = e0 + e1 + e2 + e3;
                sum += __shfl_xor(sum, 1);
                sum += __shfl_xor(sum, 2);
                sum += __shfl_xor(sum, 4);
                sum += __shfl_xor(sum, 8);
                float inv = 1.f / sum;
                sc[mi][0][r] = e0 * inv;
                sc[mi][1][r] = e1 * inv;
                sc[mi][2][r] = e2 * inv;
                sc[mi][3][r] = e3 * inv;
            }
        // ---- PV (P staged through slab) ----
        f32x4 po[4][2];
#pragma unroll
        for (int mi = 0; mi < 4; ++mi)
#pragma unroll
            for (int ni = 0; ni < 2; ++ni) po[mi][ni] = (f32x4){0.f, 0.f, 0.f, 0.f};
#pragma unroll
        for (int ks = 0; ks < 2; ++ks) {
#pragma unroll
            for (int mi = 0; mi < 4; ++mi)
#pragma unroll
                for (int r = 0; r < 4; ++r) {
                    int row = mi * 16 + g4 + r;
                    slab[row * 40 + l16]      = (__bf16)sc[mi][ks * 2 + 0][r];
                    slab[row * 40 + 16 + l16] = (__bf16)sc[mi][ks * 2 + 1][r];
                }
            bf16x8 Vf[2], Pf;
#pragma unroll
            for (int ni = 0; ni < 2; ++ni)
                Vf[ni] = *(const bf16x8*)(Vt + (ni * 16 + l16) * 72 + ks * 32 + g8);
#pragma unroll
            for (int mi = 0; mi < 4; ++mi) {
                Pf = *(const bf16x8*)(slab + (mi * 16 + l16) * 40 + g8);
#pragma unroll
                for (int ni = 0; ni < 2; ++ni)
                    po[mi][ni] = __builtin_amdgcn_mfma_f32_16x16x32_bf16(Pf, Vf[ni], po[mi][ni], 0, 0, 0);
            }
        }
        // transpose via LDS, write xr (original planar)
#pragma unroll
        for (int mi = 0; mi < 4; ++mi)
#pragma unroll
            for (int ni = 0; ni < 2; ++ni)
#pragma unroll
                for (int r = 0; r < 4; ++r)
                    Xr[(mi * 16 + g4 + r) * 36 + ni * 16 + l16] = po[mi][ni][r];
        float* xrg = xr + (size_t)(b * 96 + h * 32) * HW + pos;
#pragma unroll
        for (int c4 = 0; c4 < 8; ++c4) {
            f32x4 v = *(const f32x4*)(Xr + lane * 36 + c4 * 4);
            xrg[(size_t)(c4 * 4 + 0) * HW] = v[0];
            xrg[(size_t)(c4 * 4 + 1) * HW] = v[1];
            xrg[(size_t)(c4 * 4 + 2) * HW] = v[2];
            xrg[(size_t)(c4 * 4 + 3) * HW] = v[3];
        }
    }
}

// ---------------- K2: fused dwconv(Vs shifted) + xr + projection, in place on d_out ----
__global__ __launch_bounds__(256) void dwproj_kernel(
    const __hip_bfloat16* __restrict__ Vs, const float* __restrict__ dw_w,
    const float* __restrict__ dw_b, const float* __restrict__ WTp,
    const float* __restrict__ pb, float* __restrict__ T) {
    __shared__ float Ts[96 * 132];
    int bx0 = blockIdx.x;
    int bx = (bx0 & 7) * 512 + (bx0 >> 3);   // XCD-contiguous swizzle (4096 % 8 == 0)
    int half = bx & 1, h = (bx >> 1) & 255, b = bx >> 9;
    int w0 = half << 7;
    int tid = threadIdx.x;
    // phase 1: T[96][128] = dwconv(Vs) + xr  (xr read from T's own pixels)
    for (int task = tid; task < 1536; task += 256) {
        int c = task >> 4, g = task & 15;
        int wbase = w0 + (g << 3);
        const __hip_bfloat16* Vp = Vs + (size_t)(b * 96 + c) * HW;
        const float* wt = dw_w + c * 25;
        float acc[8];
        float bias = dw_b[c];
#pragma unroll
        for (int i = 0; i < 8; ++i) acc[i] = bias;
        bool fast = (wbase >= 8) && (wbase <= 240);
#pragma unroll
        for (int dy = -2; dy <= 2; ++dy) {
            int hh = h + dy;
            hh = hh < 0 ? -hh : (hh > 255 ? 510 - hh : hh);
            int hs = (hh + 252) & 255;
            const __hip_bfloat16* row = Vp + hs * 256;
            float xv[12];
            if (fast) {
                const uint* rp = (const uint*)(row + (wbase - 6));
#pragma unroll
                for (int g2 = 0; g2 < 6; ++g2) {
                    uint u = rp[g2];
                    xv[2 * g2]     = __uint_as_float(u << 16);
                    xv[2 * g2 + 1] = __uint_as_float(u & 0xffff0000u);
                }
            } else {
#pragma unroll
                for (int idx = 0; idx < 12; ++idx) {
                    int cw = wbase - 2 + idx;
                    cw = cw < 0 ? -cw : (cw > 255 ? 510 - cw : cw);
                    int cs = (cw + 252) & 255;
                    uint u = *(const unsigned short*)(row + cs);
                    xv[idx] = __uint_as_float(u << 16);
                }
            }
            const float* w5 = wt + (dy + 2) * 5;
#pragma unroll
            for (int dx = 0; dx < 5; ++dx) {
                float wv = w5[dx];
#pragma unroll
                for (int i = 0; i < 8; ++i) acc[i] = fmaf(wv, xv[i + dx], acc[i]);
            }
        }
        const float* xp = T + (size_t)(b * 96 + c) * HW + h * 256;
        f32x4 x0 = *(const f32x4*)(xp + wbase);
        f32x4 x1 = *(const f32x4*)(xp + wbase + 4);
#pragma unroll
        for (int i = 0; i < 4; ++i) { acc[i] += x0[i]; acc[4 + i] += x1[i]; }
        float* tr = Ts + c * 132 + (g << 3);
#pragma unroll
        for (int i = 0; i < 8; ++i) tr[i] = acc[i];
    }
    __syncthreads();
    // phase 2: projection from LDS, write out (same pixels, after barrier -> in-place safe)
    int m = tid & 127;
    int ohU = __builtin_amdgcn_readfirstlane(tid >> 7);
    for (int oc = 0; oc < 3; ++oc) {
        float acc[16];
#pragma unroll
        for (int u = 0; u < 16; ++u) acc[u] = 0.f;
        const float* wb = WTp + oc * 32 + ohU * 16;
#pragma unroll 4
        for (int c = 0; c < 96; ++c) {
            float xvv = Ts[c * 132 + m];
            const float* w = wb + c * 96;
#pragma unroll
            for (int u = 0; u < 16; ++u) acc[u] = fmaf(w[u], xvv, acc[u]);
        }
#pragma unroll
        for (int u = 0; u < 16; ++u) {
            int o = oc * 32 + ohU * 16 + u;
            T[(size_t)(b * 96 + o) * HW + h * 256 + w0 + m] = acc[u] + pb[o];
        }
    }
}

extern "C" void kernel_launch(void* const* d_in, const int* in_sizes, int n_in,
                              void* d_out, int out_size, void* d_ws, size_t ws_size,
                              hipStream_t stream) {
    const float* x      = (const float*)d_in[0];
    const float* V_w    = (const float*)d_in[1];
    const float* V_b    = (const float*)d_in[2];
    const float* QK_w   = (const float*)d_in[3];
    const float* QK_b   = (const float*)d_in[4];
    const float* proj_w = (const float*)d_in[5];
    const float* proj_b = (const float*)d_in[6];
    const float* dw_w   = (const float*)d_in[7];
    const float* dw_b   = (const float*)d_in[8];
    const float* mw1    = (const float*)d_in[9];
    const float* mb1    = (const float*)d_in[10];
    const float* mw2    = (const float*)d_in[11];
    const float* mb2    = (const float*)d_in[12];
    float* out = (float*)d_out;

    // workspace (~96.2 MiB)
    char* ws = (char*)d_ws;
    __hip_bfloat16* Vbuf = (__hip_bfloat16*)ws;                        // 100663296 B (shifted planar)
    float*  biasF = (float*)(ws + 100663296);                          // 49152 B
    __bf16* Whi   = (__bf16*)(ws + 100663296 + 49152);                 // 55296 B
    __bf16* Wlo   = (__bf16*)(ws + 100663296 + 49152 + 55296);        // 55296 B
    float*  WTproj= (float*)(ws + 100663296 + 49152 + 55296 + 55296);  // 36864 B

    bias_kernel<<<48, 256, 0, stream>>>(mw1, mb1, mw2, mb2, biasF);
    wtrans_kernel<<<144, 256, 0, stream>>>(QK_w, V_w, proj_w, Whi, Wlo, WTproj);
    fused_qkv_attn<<<2048, 256, 0, stream>>>(x, Whi, Wlo, QK_b, V_b, biasF,
                                             (unsigned short*)Vbuf, out);
    dwproj_kernel<<<4096, 256, 0, stream>>>(Vbuf, dw_w, dw_b, WTproj, proj_b, out);
}

// Round 8
// 724.714 us; speedup vs baseline: 3.1988x; 1.0852x over previous
//
#include <hip/hip_runtime.h>
#include <hip/hip_bf16.h>

#define HW 65536
#define SCALE_Q 0.17677669529663687f

typedef __bf16 bf16x8 __attribute__((ext_vector_type(8)));
typedef float f32x4 __attribute__((ext_vector_type(4)));

// ---------------- K0: rel-pos MLP bias in C-fragment layout ----------------
__global__ void bias_kernel(const float* __restrict__ w1, const float* __restrict__ b1,
                            const float* __restrict__ w2, const float* __restrict__ b2,
                            float* __restrict__ biasF) {
    int gid = blockIdx.x * blockDim.x + threadIdx.x;
    if (gid >= 12288) return;
    int lane = gid & 63, r = (gid >> 6) & 3, ni = (gid >> 8) & 3, mi = (gid >> 10) & 3, h = gid >> 12;
    int i = mi * 16 + ((lane >> 4) << 2) + r;
    int j = ni * 16 + (lane & 15);
    float di = (float)((i >> 3) - (j >> 3));
    float dj = (float)((i & 7) - (j & 7));
    float r0 = (di > 0.f ? 1.f : (di < 0.f ? -1.f : 0.f)) * log1pf(fabsf(di));
    float r1 = (dj > 0.f ? 1.f : (dj < 0.f ? -1.f : 0.f)) * log1pf(fabsf(dj));
    float acc = 0.f;
    for (int t = 0; t < 256; ++t) {
        float u = fmaf(w1[2 * t], r0, fmaf(w1[2 * t + 1], r1, b1[t]));
        u = fmaxf(u, 0.f);
        acc = fmaf(w2[h * 256 + t], u, acc);
    }
    biasF[gid] = acc + b2[h];
}

// ---------------- K0b: weight prep (bf16 hi/lo: QKV rows + proj rows) ----------
__global__ void wtrans_kernel(const float* __restrict__ QK_w, const float* __restrict__ V_w,
                              const float* __restrict__ proj_w,
                              __bf16* __restrict__ Whi, __bf16* __restrict__ Wlo,
                              __bf16* __restrict__ WpHi, __bf16* __restrict__ WpLo) {
    int idx = blockIdx.x * blockDim.x + threadIdx.x;
    if (idx < 288 * 96) {
        int oo = idx / 96, c = idx - oo * 96;
        int h = oo / 96, rem = oo - h * 96, grp = rem >> 5, d = rem & 31;
        float w = (grp == 0) ? QK_w[(h * 32 + d) * 96 + c]
                : (grp == 1) ? QK_w[(96 + h * 32 + d) * 96 + c]
                             : V_w[(h * 32 + d) * 96 + c];
        __bf16 hi = (__bf16)w;
        Whi[idx] = hi;
        Wlo[idx] = (__bf16)(w - (float)hi);
    } else if (idx < 288 * 96 + 96 * 96) {
        int rdx = idx - 288 * 96;    // proj_w is already [o][c] row-major
        float w = proj_w[rdx];
        __bf16 hi = (__bf16)w;
        WpHi[rdx] = hi;
        WpLo[rdx] = (__bf16)(w - (float)hi);
    }
}

// ---------------- K1: fused QKV conv + window attention (unchanged from r7) ----------
__global__ __launch_bounds__(256, 3) void fused_qkv_attn(
    const float* __restrict__ x,
    const __bf16* __restrict__ Whi, const __bf16* __restrict__ Wlo,
    const float* __restrict__ QK_b, const float* __restrict__ V_b,
    const float* __restrict__ biasF,
    unsigned short* __restrict__ Vout, float* __restrict__ xr) {
    __shared__ __align__(16) char lds[53376];
    int tid = threadIdx.x;
    int w4 = tid >> 6;
    int lane = tid & 63;
    int l16 = lane & 15;
    int g8 = (lane >> 4) << 3;
    int g4 = (lane >> 4) << 2;
    int bx0 = blockIdx.x;
    int bxs = (bx0 & 7) * 256 + (bx0 >> 3);
    int b = bxs >> 8;
    int wh = (bxs >> 3) & 31;
    int ww0 = (bxs & 7) << 2;
    int wh8 = wh << 3;
    int wb8 = ww0 << 3;
    int ww = ww0 + w4;
    int ti = lane >> 3, tj = lane & 7;
    int ph = (wh8 + ti + 4) & 255;
    int pw = ((ww << 3) + tj + 4) & 255;
    int pos   = ph * 256 + pw;
    int pos_s = (wh8 + ti) * 256 + (ww << 3) + tj;

    __bf16* Xh = (__bf16*)lds;
    const float* xb = x + (size_t)b * 96 * HW;
    for (int idx = tid; idx < 24576; idx += 256) {
        int c = idx >> 8, r = (idx >> 5) & 7, col = idx & 31;
        int pph = (wh8 + r + 4) & 255;
        int ppw = (wb8 + col + 4) & 255;
        Xh[(col >> 3) * 6672 + (r * 8 + (col & 7)) * 104 + c] =
            (__bf16)xb[(size_t)c * HW + pph * 256 + ppw];
    }
    __syncthreads();

    bf16x8 Ah[4][3];
    const __bf16* Xw = Xh + w4 * 6672;
#pragma unroll
    for (int mi = 0; mi < 4; ++mi)
#pragma unroll
        for (int ks = 0; ks < 3; ++ks)
            Ah[mi][ks] = *(const bf16x8*)(Xw + (mi * 16 + l16) * 104 + ks * 32 + g8);
    __syncthreads();

    char* hb = lds + w4 * 9984;
    __bf16* slab = (__bf16*)hb;
    __bf16* Vt   = (__bf16*)(hb + 5120);
    float*  Xr   = (float*)hb;

    bool bhh = (wh == 31), bww = (ww == 31);
    int rc[4];
#pragma unroll
    for (int ni = 0; ni < 4; ++ni) {
        int t = ni * 16 + l16;
        rc[ni] = (bhh ? (((t >> 3) < 4) ? 1 : 2) : 0) * 3 + (bww ? (((t & 7) < 4) ? 1 : 2) : 0);
    }

#pragma unroll 1
    for (int h = 0; h < 3; ++h) {
        bf16x8 Qf[4], Kf[4];
        {
            f32x4 acc[4][2];
#pragma unroll
            for (int mi = 0; mi < 4; ++mi)
#pragma unroll
                for (int ni = 0; ni < 2; ++ni) acc[mi][ni] = (f32x4){0.f, 0.f, 0.f, 0.f};
#pragma unroll
            for (int ks = 0; ks < 3; ++ks)
#pragma unroll
                for (int ni = 0; ni < 2; ++ni) {
                    bf16x8 Bh = *(const bf16x8*)(Whi + (h * 96 + ni * 16 + l16) * 96 + ks * 32 + g8);
#pragma unroll
                    for (int mi = 0; mi < 4; ++mi)
                        acc[mi][ni] = __builtin_amdgcn_mfma_f32_16x16x32_bf16(Ah[mi][ks], Bh, acc[mi][ni], 0, 0, 0);
                }
#pragma unroll
            for (int ni = 0; ni < 2; ++ni) {
                float bias = QK_b[h * 32 + ni * 16 + l16];
#pragma unroll
                for (int mi = 0; mi < 4; ++mi)
#pragma unroll
                    for (int r = 0; r < 4; ++r)
                        slab[(mi * 16 + g4 + r) * 40 + ni * 16 + l16] = (__bf16)((acc[mi][ni][r] + bias) * SCALE_Q);
            }
#pragma unroll
            for (int mi = 0; mi < 4; ++mi) Qf[mi] = *(const bf16x8*)(slab + (mi * 16 + l16) * 40 + g8);
        }
        {
            f32x4 acc[4][2];
#pragma unroll
            for (int mi = 0; mi < 4; ++mi)
#pragma unroll
                for (int ni = 0; ni < 2; ++ni) acc[mi][ni] = (f32x4){0.f, 0.f, 0.f, 0.f};
#pragma unroll
            for (int ks = 0; ks < 3; ++ks)
#pragma unroll
                for (int ni = 0; ni < 2; ++ni) {
                    bf16x8 Bh = *(const bf16x8*)(Whi + (h * 96 + 32 + ni * 16 + l16) * 96 + ks * 32 + g8);
#pragma unroll
                    for (int mi = 0; mi < 4; ++mi)
                        acc[mi][ni] = __builtin_amdgcn_mfma_f32_16x16x32_bf16(Ah[mi][ks], Bh, acc[mi][ni], 0, 0, 0);
                }
#pragma unroll
            for (int ni = 0; ni < 2; ++ni) {
                float bias = QK_b[96 + h * 32 + ni * 16 + l16];
#pragma unroll
                for (int mi = 0; mi < 4; ++mi)
#pragma unroll
                    for (int r = 0; r < 4; ++r)
                        slab[(mi * 16 + g4 + r) * 40 + ni * 16 + l16] = (__bf16)(acc[mi][ni][r] + bias);
            }
#pragma unroll
            for (int mi = 0; mi < 4; ++mi) Kf[mi] = *(const bf16x8*)(slab + (mi * 16 + l16) * 40 + g8);
        }
        {
            f32x4 acc[4][2];
#pragma unroll
            for (int mi = 0; mi < 4; ++mi)
#pragma unroll
                for (int ni = 0; ni < 2; ++ni) acc[mi][ni] = (f32x4){0.f, 0.f, 0.f, 0.f};
#pragma unroll
            for (int ks = 0; ks < 3; ++ks)
#pragma unroll
                for (int ni = 0; ni < 2; ++ni) {
                    int oo = (h * 96 + 64 + ni * 16 + l16) * 96 + ks * 32 + g8;
                    bf16x8 Bh = *(const bf16x8*)(Whi + oo);
                    bf16x8 Bl = *(const bf16x8*)(Wlo + oo);
#pragma unroll
                    for (int mi = 0; mi < 4; ++mi) {
                        acc[mi][ni] = __builtin_amdgcn_mfma_f32_16x16x32_bf16(Ah[mi][ks], Bh, acc[mi][ni], 0, 0, 0);
                        acc[mi][ni] = __builtin_amdgcn_mfma_f32_16x16x32_bf16(Ah[mi][ks], Bl, acc[mi][ni], 0, 0, 0);
                    }
                }
#pragma unroll
            for (int ni = 0; ni < 2; ++ni) {
                float bias = V_b[h * 32 + ni * 16 + l16];
#pragma unroll
                for (int mi = 0; mi < 4; ++mi)
#pragma unroll
                    for (int r = 0; r < 4; ++r)
                        Vt[(ni * 16 + l16) * 72 + mi * 16 + g4 + r] = (__bf16)(acc[mi][ni][r] + bias);
            }
        }
#pragma unroll
        for (int d = 0; d < 32; ++d)
            Vout[(size_t)(b * 96 + h * 32 + d) * HW + pos_s] = ((const unsigned short*)Vt)[d * 72 + lane];

        f32x4 sc[4][4];
#pragma unroll
        for (int mi = 0; mi < 4; ++mi)
#pragma unroll
            for (int ni = 0; ni < 4; ++ni) {
                sc[mi][ni] = (f32x4){0.f, 0.f, 0.f, 0.f};
                sc[mi][ni] = __builtin_amdgcn_mfma_f32_16x16x32_bf16(Qf[mi], Kf[ni], sc[mi][ni], 0, 0, 0);
            }
        const float* bF = biasF + h * 4096;
#pragma unroll
        for (int mi = 0; mi < 4; ++mi)
#pragma unroll
            for (int r = 0; r < 4; ++r) {
                int row = mi * 16 + g4 + r;
                float s0 = sc[mi][0][r] + bF[((mi * 4 + 0) * 4 + r) * 64 + lane];
                float s1 = sc[mi][1][r] + bF[((mi * 4 + 1) * 4 + r) * 64 + lane];
                float s2 = sc[mi][2][r] + bF[((mi * 4 + 2) * 4 + r) * 64 + lane];
                float s3 = sc[mi][3][r] + bF[((mi * 4 + 3) * 4 + r) * 64 + lane];
                if (bhh || bww) {
                    int rr = (bhh ? (((row >> 3) < 4) ? 1 : 2) : 0) * 3 +
                             (bww ? (((row & 7) < 4) ? 1 : 2) : 0);
                    if (rr != rc[0]) s0 -= 100.f;
                    if (rr != rc[1]) s1 -= 100.f;
                    if (rr != rc[2]) s2 -= 100.f;
                    if (rr != rc[3]) s3 -= 100.f;
                }
                float mm = fmaxf(fmaxf(s0, s1), fmaxf(s2, s3));
                mm = fmaxf(mm, __shfl_xor(mm, 1));
                mm = fmaxf(mm, __shfl_xor(mm, 2));
                mm = fmaxf(mm, __shfl_xor(mm, 4));
                mm = fmaxf(mm, __shfl_xor(mm, 8));
                float e0 = __expf(s0 - mm), e1 = __expf(s1 - mm);
                float e2 = __expf(s2 - mm), e3 = __expf(s3 - mm);
                float sum = e0 + e1 + e2 + e3;
                sum += __shfl_xor(sum, 1);
                sum += __shfl_xor(sum, 2);
                sum += __shfl_xor(sum, 4);
                sum += __shfl_xor(sum, 8);
                float inv = 1.f / sum;
                sc[mi][0][r] = e0 * inv;
                sc[mi][1][r] = e1 * inv;
                sc[mi][2][r] = e2 * inv;
                sc[mi][3][r] = e3 * inv;
            }
        f32x4 po[4][2];
#pragma unroll
        for (int mi = 0; mi < 4; ++mi)
#pragma unroll
            for (int ni = 0; ni < 2; ++ni) po[mi][ni] = (f32x4){0.f, 0.f, 0.f, 0.f};
#pragma unroll
        for (int ks = 0; ks < 2; ++ks) {
#pragma unroll
            for (int mi = 0; mi < 4; ++mi)
#pragma unroll
                for (int r = 0; r < 4; ++r) {
                    int row = mi * 16 + g4 + r;
                    slab[row * 40 + l16]      = (__bf16)sc[mi][ks * 2 + 0][r];
                    slab[row * 40 + 16 + l16] = (__bf16)sc[mi][ks * 2 + 1][r];
                }
            bf16x8 Vf[2], Pf;
#pragma unroll
            for (int ni = 0; ni < 2; ++ni)
                Vf[ni] = *(const bf16x8*)(Vt + (ni * 16 + l16) * 72 + ks * 32 + g8);
#pragma unroll
            for (int mi = 0; mi < 4; ++mi) {
                Pf = *(const bf16x8*)(slab + (mi * 16 + l16) * 40 + g8);
#pragma unroll
                for (int ni = 0; ni < 2; ++ni)
                    po[mi][ni] = __builtin_amdgcn_mfma_f32_16x16x32_bf16(Pf, Vf[ni], po[mi][ni], 0, 0, 0);
            }
        }
#pragma unroll
        for (int mi = 0; mi < 4; ++mi)
#pragma unroll
            for (int ni = 0; ni < 2; ++ni)
#pragma unroll
                for (int r = 0; r < 4; ++r)
                    Xr[(mi * 16 + g4 + r) * 36 + ni * 16 + l16] = po[mi][ni][r];
        float* xrg = xr + (size_t)(b * 96 + h * 32) * HW + pos;
#pragma unroll
        for (int c4 = 0; c4 < 8; ++c4) {
            f32x4 v = *(const f32x4*)(Xr + lane * 36 + c4 * 4);
            xrg[(size_t)(c4 * 4 + 0) * HW] = v[0];
            xrg[(size_t)(c4 * 4 + 1) * HW] = v[1];
            xrg[(size_t)(c4 * 4 + 2) * HW] = v[2];
            xrg[(size_t)(c4 * 4 + 3) * HW] = v[3];
        }
    }
}

// ---------------- K2: fused dwconv + xr -> LDS, then MFMA projection (in place) ----
__global__ __launch_bounds__(256) void dwproj_kernel(
    const __hip_bfloat16* __restrict__ Vs, const float* __restrict__ dw_w,
    const float* __restrict__ dw_b, const __bf16* __restrict__ WpHi,
    const __bf16* __restrict__ WpLo, const float* __restrict__ pb,
    float* __restrict__ T) {
    __shared__ __align__(16) float Ts[12800];   // [128 px][100] f32, rows 400 B (16B-aligned)
    int bx0 = blockIdx.x;
    int bx = (bx0 & 7) * 512 + (bx0 >> 3);   // XCD-contiguous rows
    int half = bx & 1, h = (bx >> 1) & 255, b = bx >> 9;
    int w0 = half << 7;
    int tid = threadIdx.x;
    // phase 1: Ts[px][c] = dwconv(Vs) + xr (f32)
    for (int task = tid; task < 1536; task += 256) {
        int c = task >> 4, g = task & 15;
        int wbase = w0 + (g << 3);
        const __hip_bfloat16* Vp = Vs + (size_t)(b * 96 + c) * HW;
        const float* wt = dw_w + c * 25;
        float acc[8];
        float bias = dw_b[c];
#pragma unroll
        for (int i = 0; i < 8; ++i) acc[i] = bias;
        bool fast = (wbase >= 8) && (wbase <= 240);
#pragma unroll
        for (int dy = -2; dy <= 2; ++dy) {
            int hh = h + dy;
            hh = hh < 0 ? -hh : (hh > 255 ? 510 - hh : hh);
            int hs = (hh + 252) & 255;
            const __hip_bfloat16* row = Vp + hs * 256;
            float xv[12];
            if (fast) {
                const uint* rp = (const uint*)(row + (wbase - 6));
#pragma unroll
                for (int g2 = 0; g2 < 6; ++g2) {
                    uint u = rp[g2];
                    xv[2 * g2]     = __uint_as_float(u << 16);
                    xv[2 * g2 + 1] = __uint_as_float(u & 0xffff0000u);
                }
            } else {
#pragma unroll
                for (int idx = 0; idx < 12; ++idx) {
                    int cw = wbase - 2 + idx;
                    cw = cw < 0 ? -cw : (cw > 255 ? 510 - cw : cw);
                    int cs = (cw + 252) & 255;
                    uint u = *(const unsigned short*)(row + cs);
                    xv[idx] = __uint_as_float(u << 16);
                }
            }
            const float* w5 = wt + (dy + 2) * 5;
#pragma unroll
            for (int dx = 0; dx < 5; ++dx) {
                float wv = w5[dx];
#pragma unroll
                for (int i = 0; i < 8; ++i) acc[i] = fmaf(wv, xv[i + dx], acc[i]);
            }
        }
        const float* xp = T + (size_t)(b * 96 + c) * HW + h * 256;
        f32x4 x0 = *(const f32x4*)(xp + wbase);
        f32x4 x1 = *(const f32x4*)(xp + wbase + 4);
#pragma unroll
        for (int i = 0; i < 4; ++i) { acc[i] += x0[i]; acc[4 + i] += x1[i]; }
#pragma unroll
        for (int i = 0; i < 8; ++i) Ts[(g * 8 + i) * 100 + c] = acc[i];
    }
    __syncthreads();
    // phase 2: MFMA projection [128px x 96c] x [96c x 96o], hi/lo 3-pass
    int lane = tid & 63;
    int l16 = lane & 15;
    int g8 = (lane >> 4) << 3;
    int g4 = (lane >> 4) << 2;
    int wv = tid >> 6;   // wave 0..3 -> rows [wv*32, wv*32+32)
    f32x4 po[2][6];
#pragma unroll
    for (int mi = 0; mi < 2; ++mi)
#pragma unroll
        for (int ni = 0; ni < 6; ++ni) po[mi][ni] = (f32x4){0.f, 0.f, 0.f, 0.f};
#pragma unroll
    for (int ks = 0; ks < 3; ++ks) {
        bf16x8 Ah[2], Al[2];
#pragma unroll
        for (int mi = 0; mi < 2; ++mi) {
            const float* ap = Ts + (wv * 32 + mi * 16 + l16) * 100 + ks * 32 + g8;
            f32x4 a0 = *(const f32x4*)ap;
            f32x4 a1 = *(const f32x4*)(ap + 4);
#pragma unroll
            for (int e = 0; e < 4; ++e) {
                float f0 = a0[e];
                __bf16 h0 = (__bf16)f0;
                Ah[mi][e] = h0;
                Al[mi][e] = (__bf16)(f0 - (float)h0);
                float f1 = a1[e];
                __bf16 h1 = (__bf16)f1;
                Ah[mi][4 + e] = h1;
                Al[mi][4 + e] = (__bf16)(f1 - (float)h1);
            }
        }
#pragma unroll
        for (int ni = 0; ni < 6; ++ni) {
            int o = ni * 16 + l16;
            bf16x8 Bh = *(const bf16x8*)(WpHi + o * 96 + ks * 32 + g8);
            bf16x8 Bl = *(const bf16x8*)(WpLo + o * 96 + ks * 32 + g8);
#pragma unroll
            for (int mi = 0; mi < 2; ++mi) {
                po[mi][ni] = __builtin_amdgcn_mfma_f32_16x16x32_bf16(Ah[mi], Bh, po[mi][ni], 0, 0, 0);
                po[mi][ni] = __builtin_amdgcn_mfma_f32_16x16x32_bf16(Al[mi], Bh, po[mi][ni], 0, 0, 0);
                po[mi][ni] = __builtin_amdgcn_mfma_f32_16x16x32_bf16(Ah[mi], Bl, po[mi][ni], 0, 0, 0);
            }
        }
    }
    // epilogue: bias + aligned float4 stores (in place, after barrier)
#pragma unroll
    for (int ni = 0; ni < 6; ++ni) {
        int o = ni * 16 + l16;
        float bias = pb[o];
#pragma unroll
        for (int mi = 0; mi < 2; ++mi) {
            f32x4 v = po[mi][ni];
            v[0] += bias; v[1] += bias; v[2] += bias; v[3] += bias;
            *(f32x4*)(T + (size_t)(b * 96 + o) * HW + h * 256 + w0 + wv * 32 + mi * 16 + g4) = v;
        }
    }
}

extern "C" void kernel_launch(void* const* d_in, const int* in_sizes, int n_in,
                              void* d_out, int out_size, void* d_ws, size_t ws_size,
                              hipStream_t stream) {
    const float* x      = (const float*)d_in[0];
    const float* V_w    = (const float*)d_in[1];
    const float* V_b    = (const float*)d_in[2];
    const float* QK_w   = (const float*)d_in[3];
    const float* QK_b   = (const float*)d_in[4];
    const float* proj_w = (const float*)d_in[5];
    const float* proj_b = (const float*)d_in[6];
    const float* dw_w   = (const float*)d_in[7];
    const float* dw_b   = (const float*)d_in[8];
    const float* mw1    = (const float*)d_in[9];
    const float* mb1    = (const float*)d_in[10];
    const float* mw2    = (const float*)d_in[11];
    const float* mb2    = (const float*)d_in[12];
    float* out = (float*)d_out;

    // workspace (~96.2 MiB)
    char* ws = (char*)d_ws;
    __hip_bfloat16* Vbuf = (__hip_bfloat16*)ws;                         // 100663296 B (shifted planar)
    float*  biasF = (float*)(ws + 100663296);                           // 49152 B
    __bf16* Whi   = (__bf16*)(ws + 100663296 + 49152);                  // 55296 B
    __bf16* Wlo   = (__bf16*)(ws + 100663296 + 49152 + 55296);          // 55296 B
    __bf16* WpHi  = (__bf16*)(ws + 100663296 + 49152 + 2 * 55296);      // 18432 B
    __bf16* WpLo  = (__bf16*)(ws + 100663296 + 49152 + 2 * 55296 + 18432); // 18432 B

    bias_kernel<<<48, 256, 0, stream>>>(mw1, mb1, mw2, mb2, biasF);
    wtrans_kernel<<<144, 256, 0, stream>>>(QK_w, V_w, proj_w, Whi, Wlo, WpHi, WpLo);
    fused_qkv_attn<<<2048, 256, 0, stream>>>(x, Whi, Wlo, QK_b, V_b, biasF,
                                             (unsigned short*)Vbuf, out);
    dwproj_kernel<<<4096, 256, 0, stream>>>(Vbuf, dw_w, dw_b, WpHi, WpLo, proj_b, out);
}